// Round 7
// baseline (526.304 us; speedup 1.0000x reference)
//
#include <hip/hip_runtime.h>
#include <hip/hip_bf16.h>
#include <math.h>

#define CDIM 768
#define HDIM 3072
#define NROWS 4096   // B*T
#define TSEQ 2048
#define NHEAD 12

typedef unsigned short u16;
typedef unsigned int   u32;
typedef __attribute__((ext_vector_type(8))) short short8;
typedef __attribute__((ext_vector_type(4))) float f32x4;

#define L2E 1.4426950408889634f

static __device__ __forceinline__ u16 f2bf(float f) {
    u32 x = __float_as_uint(f);
    x += 0x7fffu + ((x >> 16) & 1u);
    return (u16)(x >> 16);
}

#define GLL16(g, l)                                                            \
    __builtin_amdgcn_global_load_lds(                                          \
        (const __attribute__((address_space(1))) void*)(g),                    \
        (__attribute__((address_space(3))) void*)(l), 16, 0, 0)

static __device__ __forceinline__ float redmax16(float v) {
#pragma unroll
    for (int m = 1; m < 16; m <<= 1) v = fmaxf(v, __shfl_xor(v, m));
    return v;
}
static __device__ __forceinline__ float redsum16(float v) {
#pragma unroll
    for (int m = 1; m < 16; m <<= 1) v += __shfl_xor(v, m);
    return v;
}

// ---------------------------------------------------------------- transpose
// w [K,N] fp32 -> wt [N,K] bf16
__launch_bounds__(256)
__global__ void wtrans(const float* __restrict__ w, u16* __restrict__ wt,
                       int K, int N) {
    __shared__ float t[32][33];
    const int n0 = blockIdx.x * 32, k0 = blockIdx.y * 32;
    const int tx = threadIdx.x & 31, ty = threadIdx.x >> 5;  // 32 x 8
#pragma unroll
    for (int i = ty; i < 32; i += 8)
        t[i][tx] = w[(size_t)(k0 + i) * N + n0 + tx];
    __syncthreads();
#pragma unroll
    for (int i = ty; i < 32; i += 8)
        wt[(size_t)(n0 + i) * K + k0 + tx] = f2bf(t[tx][i]);
}

// ---------------------------------------------------------------- fp32 -> bf16 copy
__launch_bounds__(256)
__global__ void cvt_copy(const float* __restrict__ in, u16* __restrict__ out,
                         int n4) {
    int i = blockIdx.x * 256 + threadIdx.x;
    if (i >= n4) return;
    float4 v = ((const float4*)in)[i];
    ushort4 o;
    o.x = f2bf(v.x); o.y = f2bf(v.y); o.z = f2bf(v.z); o.w = f2bf(v.w);
    ((ushort4*)out)[i] = o;
}

// ---------------------------------------------------------------- layernorm
__launch_bounds__(256)
__global__ void ln_kernel(const float* __restrict__ x, const float* __restrict__ g,
                          const float* __restrict__ bta, u16* __restrict__ out) {
    const int row = blockIdx.x, tid = threadIdx.x;
    const float* xr = x + (size_t)row * CDIM;
    float v0 = xr[tid], v1 = xr[tid + 256], v2 = xr[tid + 512];
    __shared__ float red[8];
    float s = v0 + v1 + v2;
#pragma unroll
    for (int m = 1; m < 64; m <<= 1) s += __shfl_xor(s, m);
    if ((tid & 63) == 0) red[tid >> 6] = s;
    __syncthreads();
    const float mu = (red[0] + red[1] + red[2] + red[3]) * (1.f / CDIM);
    const float d0 = v0 - mu, d1 = v1 - mu, d2 = v2 - mu;
    float q = d0 * d0 + d1 * d1 + d2 * d2;
#pragma unroll
    for (int m = 1; m < 64; m <<= 1) q += __shfl_xor(q, m);
    if ((tid & 63) == 0) red[4 + (tid >> 6)] = q;
    __syncthreads();
    const float var = (red[4] + red[5] + red[6] + red[7]) * (1.f / CDIM);
    const float rstd = rsqrtf(var + 1e-5f);
    u16* orow = out + (size_t)row * CDIM;
    orow[tid]       = f2bf(d0 * rstd * g[tid]       + bta[tid]);
    orow[tid + 256] = f2bf(d1 * rstd * g[tid + 256] + bta[tid + 256]);
    orow[tid + 512] = f2bf(d2 * rstd * g[tid + 512] + bta[tid + 512]);
}

// ---------------------------------------------------------------- GEMM
// C[M,N] = A[M,K](bf16) * BT[N,K]^T(bf16) + bias, epilogue variants.
// 128x128 tile, BK=32, 4 waves (each 64x64), global_load_lds staging (m97).
struct GemmArgs {
    const u16* A[3];
    const u16* BT[3];
    const float* bias[3];
    const float* res[3];
    void* out[3];
    float alpha[3];
    int M, N, K;
};

// EPI: 0 = (s+bias)*alpha -> bf16 ; 1 = res + s + bias -> f32 ;
//      2 = gelu(s+bias) -> bf16
template <int EPI>
__launch_bounds__(256)
__global__ void gemm_bt(GemmArgs ga) {
    __shared__ u16 Abuf[128 * 32];
    __shared__ u16 Bbuf[128 * 32];
    const int z = blockIdx.z;
    const u16* __restrict__ A  = ga.A[z];
    const u16* __restrict__ BT = ga.BT[z];
    const float* __restrict__ bias = ga.bias[z];
    const float* __restrict__ res  = ga.res[z];
    void* outv = ga.out[z];
    const float alpha = ga.alpha[z];
    const int N = ga.N, K = ga.K;

    const int tid = threadIdx.x;
    const int lane = tid & 63, w = tid >> 6;
    const int m0 = blockIdx.x * 128, n0 = blockIdx.y * 128;
    const int wr = (w >> 1) * 64, wc = (w & 1) * 64;
    const int lr = lane & 15, lc = lane >> 4;

    const int srow = w * 32 + (lane >> 2);
    const int scol = (lane & 3) * 8;
    const u16* Ag = A + (size_t)(m0 + srow) * K + scol;
    const u16* Bg = BT + (size_t)(n0 + srow) * K + scol;
    char* Ab = (char*)Abuf + w * 2048;
    char* Bb = (char*)Bbuf + w * 2048;

    f32x4 acc[4][4];
#pragma unroll
    for (int m = 0; m < 4; ++m)
#pragma unroll
        for (int n = 0; n < 4; ++n) acc[m][n] = (f32x4){0.f, 0.f, 0.f, 0.f};

    const int nk = K >> 5;
    for (int kt = 0; kt < nk; ++kt) {
        const int ko = kt * 32;
        GLL16(Ag + ko,          Ab);
        GLL16(Ag + 16 * K + ko, Ab + 1024);
        GLL16(Bg + ko,          Bb);
        GLL16(Bg + 16 * K + ko, Bb + 1024);
        __syncthreads();
        short8 af[4], bfv[4];
#pragma unroll
        for (int m = 0; m < 4; ++m)
            af[m] = *(const short8*)((const char*)Abuf +
                                     (size_t)(wr + m * 16 + lr) * 64 + lc * 16);
#pragma unroll
        for (int n = 0; n < 4; ++n)
            bfv[n] = *(const short8*)((const char*)Bbuf +
                                      (size_t)(wc + n * 16 + lr) * 64 + lc * 16);
#pragma unroll
        for (int m = 0; m < 4; ++m)
#pragma unroll
            for (int n = 0; n < 4; ++n)
                acc[m][n] = __builtin_amdgcn_mfma_f32_16x16x32_bf16(
                    af[m], bfv[n], acc[m][n], 0, 0, 0);
        __syncthreads();
    }

    // epilogue: C/D layout col=lane&15, row=(lane>>4)*4+reg
#pragma unroll
    for (int n = 0; n < 4; ++n) {
        const int gc = n0 + wc + n * 16 + lr;
        const float bs = bias[gc];
#pragma unroll
        for (int m = 0; m < 4; ++m) {
            const int gr = m0 + wr + m * 16 + lc * 4;
#pragma unroll
            for (int r = 0; r < 4; ++r) {
                float v = (acc[m][n][r] + bs) * alpha;
                const size_t idx = (size_t)(gr + r) * N + gc;
                if constexpr (EPI == 0) {
                    ((u16*)outv)[idx] = f2bf(v);
                } else if constexpr (EPI == 1) {
                    ((float*)outv)[idx] = res[idx] + v;
                } else {
                    float gel = 0.5f * v * (1.0f + erff(v * 0.70710678118654752f));
                    ((u16*)outv)[idx] = f2bf(gel);
                }
            }
        }
    }
}

// ---------------------------------------------------------------- attention
// Flash attention, 64 q-rows per block (4 waves x 16 rows), KBLK=64, dh=64.
// Q pre-scaled by 1/sqrt(dh) in the projection epilogue.
__launch_bounds__(256)
__global__ void attn_kernel(const u16* __restrict__ Qb, const u16* __restrict__ Kb,
                            const u16* __restrict__ Vb, u16* __restrict__ Ob) {
    __shared__ u16 Klds[64 * 72];      // K-tile rows, padded to 72 elems (144B)
    __shared__ u16 Vt[64 * 72];        // V-tile transposed: [d][k]
    __shared__ u16 Plds[4][16 * 72];   // per-wave P redistribution buffer
    const int tid = threadIdx.x;
    const int lane = tid & 63, w = tid >> 6;
    const int lr = lane & 15, lc = lane >> 4;
    const int b = blockIdx.y / NHEAD, h = blockIdx.y % NHEAD;
    const size_t qrow0 = (size_t)b * TSEQ + blockIdx.x * 64 + w * 16;
    const size_t krow0 = (size_t)b * TSEQ;
    const int hc = h * 64;

    short8 qf0, qf1;
    {
        const u16* qp = Qb + (qrow0 + lr) * CDIM + hc + lc * 8;
        qf0 = *(const short8*)qp;
        qf1 = *(const short8*)(qp + 32);
    }
    f32x4 oacc[4];
    float mrow[4], lrow[4];
#pragma unroll
    for (int r = 0; r < 4; ++r) {
        oacc[r] = (f32x4){0.f, 0.f, 0.f, 0.f};
        mrow[r] = -3e38f;
        lrow[r] = 0.f;
    }

    const int stg_r = tid >> 2, stg_s = tid & 3;

    for (int kt = 0; kt < TSEQ / 64; ++kt) {
        __syncthreads();
        {   // stage K-tile (row-major) and V-tile (transposed)
            const u16* kg = Kb + (krow0 + kt * 64 + stg_r) * CDIM + hc + stg_s * 16;
            uint4 a0 = *(const uint4*)kg;
            uint4 a1 = *(const uint4*)(kg + 8);
            *(uint4*)&Klds[stg_r * 72 + stg_s * 16]     = a0;
            *(uint4*)&Klds[stg_r * 72 + stg_s * 16 + 8] = a1;
            const u16* vg = Vb + (krow0 + kt * 64 + stg_r) * CDIM + hc + stg_s * 16;
            uint4 b0 = *(const uint4*)vg;
            uint4 b1 = *(const uint4*)(vg + 8);
            u16 tmp[16];
            *(uint4*)(tmp)     = b0;
            *(uint4*)(tmp + 8) = b1;
#pragma unroll
            for (int j = 0; j < 16; ++j)
                Vt[(stg_s * 16 + j) * 72 + stg_r] = tmp[j];
        }
        __syncthreads();

        // S = Q * K^T
        f32x4 sf[4];
#pragma unroll
        for (int fn = 0; fn < 4; ++fn) {
            const u16* kr = &Klds[(lr + fn * 16) * 72 + lc * 8];
            short8 kb0 = *(const short8*)kr;
            short8 kb1 = *(const short8*)(kr + 32);
            f32x4 t = (f32x4){0.f, 0.f, 0.f, 0.f};
            t = __builtin_amdgcn_mfma_f32_16x16x32_bf16(qf0, kb0, t, 0, 0, 0);
            t = __builtin_amdgcn_mfma_f32_16x16x32_bf16(qf1, kb1, t, 0, 0, 0);
            sf[fn] = t;
        }

        // online softmax (row = (lane>>4)*4 + r, col = lane&15 + 16*fn)
#pragma unroll
        for (int r = 0; r < 4; ++r) {
            float pm = fmaxf(fmaxf(sf[0][r], sf[1][r]), fmaxf(sf[2][r], sf[3][r]));
            pm = redmax16(pm);
            const float mn = fmaxf(mrow[r], pm);
            const float corr = exp2f((mrow[r] - mn) * L2E);
            mrow[r] = mn;
            float rs = 0.f;
#pragma unroll
            for (int fn = 0; fn < 4; ++fn) {
                float p = exp2f((sf[fn][r] - mn) * L2E);
                sf[fn][r] = p;
                rs += p;
            }
            rs = redsum16(rs);
            lrow[r] = lrow[r] * corr + rs;
#pragma unroll
            for (int fd = 0; fd < 4; ++fd) oacc[fd][r] *= corr;
#pragma unroll
            for (int fn = 0; fn < 4; ++fn)
                Plds[w][(lc * 4 + r) * 72 + lr + fn * 16] = f2bf(sf[fn][r]);
        }
        asm volatile("s_waitcnt lgkmcnt(0)" ::: "memory");
        __builtin_amdgcn_sched_barrier(0);

        // O += P * V
        short8 pa0 = *(const short8*)&Plds[w][lr * 72 + lc * 8];
        short8 pa1 = *(const short8*)&Plds[w][lr * 72 + lc * 8 + 32];
#pragma unroll
        for (int fd = 0; fd < 4; ++fd) {
            const u16* vr = &Vt[(lr + fd * 16) * 72 + lc * 8];
            short8 vb0 = *(const short8*)vr;
            short8 vb1 = *(const short8*)(vr + 32);
            oacc[fd] = __builtin_amdgcn_mfma_f32_16x16x32_bf16(pa0, vb0, oacc[fd], 0, 0, 0);
            oacc[fd] = __builtin_amdgcn_mfma_f32_16x16x32_bf16(pa1, vb1, oacc[fd], 0, 0, 0);
        }
    }

#pragma unroll
    for (int fd = 0; fd < 4; ++fd) {
#pragma unroll
        for (int r = 0; r < 4; ++r) {
            float v = oacc[fd][r] / lrow[r];
            Ob[(qrow0 + lc * 4 + r) * CDIM + hc + fd * 16 + lr] = f2bf(v);
        }
    }
}

// ---------------------------------------------------------------- launch
extern "C" void kernel_launch(void* const* d_in, const int* in_sizes, int n_in,
                              void* d_out, int out_size, void* d_ws, size_t ws_size,
                              hipStream_t stream) {
    const float* x     = (const float*)d_in[0];
    const float* ctx   = (const float*)d_in[1];
    const float* ln1g  = (const float*)d_in[2];
    const float* ln1b  = (const float*)d_in[3];
    const float* ln2g  = (const float*)d_in[4];
    const float* ln2b  = (const float*)d_in[5];
    const float* ln3g  = (const float*)d_in[6];
    const float* ln3b  = (const float*)d_in[7];
    const float* sa_wq = (const float*)d_in[8];
    const float* sa_bq = (const float*)d_in[9];
    const float* sa_wk = (const float*)d_in[10];
    const float* sa_bk = (const float*)d_in[11];
    const float* sa_wv = (const float*)d_in[12];
    const float* sa_bv = (const float*)d_in[13];
    const float* sa_wo = (const float*)d_in[14];
    const float* sa_bo = (const float*)d_in[15];
    const float* xa_wq = (const float*)d_in[16];
    const float* xa_bq = (const float*)d_in[17];
    const float* xa_wk = (const float*)d_in[18];
    const float* xa_bk = (const float*)d_in[19];
    const float* xa_wv = (const float*)d_in[20];
    const float* xa_bv = (const float*)d_in[21];
    const float* xa_wo = (const float*)d_in[22];
    const float* xa_bo = (const float*)d_in[23];
    const float* m_w1  = (const float*)d_in[24];
    const float* m_b1  = (const float*)d_in[25];
    const float* m_w2  = (const float*)d_in[26];
    const float* m_b2  = (const float*)d_in[27];

    // OUTPUT IS FP32 (reference returns float32): out = [x (4096x768 f32), context (4096x768 f32)]
    float* out_x   = (float*)d_out;
    float* out_ctx = out_x + (size_t)NROWS * CDIM;

    // ---- workspace plan (aliased, 48,758,784 bytes; rounds 4-6 confirmed fits) ----
    const size_t SZ_ACT = (size_t)NROWS * CDIM * 2;   //  6,291,456
    const size_t SZ_WBIG = (size_t)HDIM * CDIM * 2;   //  4,718,592
    const size_t SZ_R   = (size_t)NROWS * CDIM * 4;   // 12,582,912
    const size_t NEEDED = 5 * SZ_ACT + SZ_R + SZ_WBIG;
    if (ws_size < NEEDED) return;  // diagnostic: error==5.406 => ws too small

    char* ws = (char*)d_ws;
    u16* qb    = (u16*)(ws);                       // hb aliases [0, 4*SZ_ACT)
    u16* kb    = (u16*)(ws + 1 * SZ_ACT);
    u16* vb    = (u16*)(ws + 2 * SZ_ACT);
    u16* ctxb  = (u16*)(ws + 3 * SZ_ACT);          // bf16 context (dead by MLP)
    u16* hb    = qb;                               // 4096*3072 bf16 = 4*SZ_ACT
    u16* lnbuf = (u16*)(ws + 4 * SZ_ACT);
    u16* attB  = lnbuf;                            // alias: dead phases disjoint
    float* R   = (float*)(ws + 5 * SZ_ACT);
    u16* Wq    = (u16*)(ws + 5 * SZ_ACT + SZ_R);   // weight pool (SZ_WBIG)
    u16* Wk    = Wq + (size_t)CDIM * CDIM;
    u16* Wv    = Wk + (size_t)CDIM * CDIM;

    const dim3 tb(256);
    GemmArgs ga;

    // output #2: context passthrough (fp32), and internal bf16 copy for XA K/V
    hipMemcpyAsync(out_ctx, ctx, (size_t)NROWS * CDIM * 4,
                   hipMemcpyDeviceToDevice, stream);
    cvt_copy<<<dim3(3072), tb, 0, stream>>>(ctx, ctxb, NROWS * CDIM / 4);

    // ---- self-attention
    ln_kernel<<<dim3(NROWS), tb, 0, stream>>>(x, ln1g, ln1b, lnbuf);
    wtrans<<<dim3(24, 24), tb, 0, stream>>>(sa_wq, Wq, 768, 768);
    wtrans<<<dim3(24, 24), tb, 0, stream>>>(sa_wk, Wk, 768, 768);
    wtrans<<<dim3(24, 24), tb, 0, stream>>>(sa_wv, Wv, 768, 768);
    ga = GemmArgs{};
    ga.A[0] = lnbuf; ga.BT[0] = Wq; ga.bias[0] = sa_bq; ga.out[0] = qb; ga.alpha[0] = 0.125f;
    ga.A[1] = lnbuf; ga.BT[1] = Wk; ga.bias[1] = sa_bk; ga.out[1] = kb; ga.alpha[1] = 1.f;
    ga.A[2] = lnbuf; ga.BT[2] = Wv; ga.bias[2] = sa_bv; ga.out[2] = vb; ga.alpha[2] = 1.f;
    ga.M = 4096; ga.N = 768; ga.K = 768;
    gemm_bt<0><<<dim3(32, 6, 3), tb, 0, stream>>>(ga);
    attn_kernel<<<dim3(32, 24), tb, 0, stream>>>(qb, kb, vb, attB);
    wtrans<<<dim3(24, 24), tb, 0, stream>>>(sa_wo, Wq, 768, 768);
    ga = GemmArgs{};
    ga.A[0] = attB; ga.BT[0] = Wq; ga.bias[0] = sa_bo; ga.res[0] = x; ga.out[0] = R; ga.alpha[0] = 1.f;
    ga.M = 4096; ga.N = 768; ga.K = 768;
    gemm_bt<1><<<dim3(32, 6, 1), tb, 0, stream>>>(ga);

    // ---- cross-attention
    ln_kernel<<<dim3(NROWS), tb, 0, stream>>>(R, ln2g, ln2b, lnbuf);
    wtrans<<<dim3(24, 24), tb, 0, stream>>>(xa_wq, Wq, 768, 768);
    wtrans<<<dim3(24, 24), tb, 0, stream>>>(xa_wk, Wk, 768, 768);
    wtrans<<<dim3(24, 24), tb, 0, stream>>>(xa_wv, Wv, 768, 768);
    ga = GemmArgs{};
    ga.A[0] = lnbuf; ga.BT[0] = Wq; ga.bias[0] = xa_bq; ga.out[0] = qb; ga.alpha[0] = 0.125f;
    ga.A[1] = ctxb;  ga.BT[1] = Wk; ga.bias[1] = xa_bk; ga.out[1] = kb; ga.alpha[1] = 1.f;
    ga.A[2] = ctxb;  ga.BT[2] = Wv; ga.bias[2] = xa_bv; ga.out[2] = vb; ga.alpha[2] = 1.f;
    ga.M = 4096; ga.N = 768; ga.K = 768;
    gemm_bt<0><<<dim3(32, 6, 3), tb, 0, stream>>>(ga);
    attn_kernel<<<dim3(32, 24), tb, 0, stream>>>(qb, kb, vb, attB);
    wtrans<<<dim3(24, 24), tb, 0, stream>>>(xa_wo, Wq, 768, 768);
    ga = GemmArgs{};
    ga.A[0] = attB; ga.BT[0] = Wq; ga.bias[0] = xa_bo; ga.res[0] = R; ga.out[0] = R; ga.alpha[0] = 1.f;
    ga.M = 4096; ga.N = 768; ga.K = 768;
    gemm_bt<1><<<dim3(32, 6, 1), tb, 0, stream>>>(ga);

    // ---- MLP
    ln_kernel<<<dim3(NROWS), tb, 0, stream>>>(R, ln3g, ln3b, lnbuf);
    wtrans<<<dim3(96, 24), tb, 0, stream>>>(m_w1, Wq, 768, 3072);  // full pool
    ga = GemmArgs{};
    ga.A[0] = lnbuf; ga.BT[0] = Wq; ga.bias[0] = m_b1; ga.out[0] = hb; ga.alpha[0] = 1.f;
    ga.M = 4096; ga.N = 3072; ga.K = 768;
    gemm_bt<2><<<dim3(32, 24, 1), tb, 0, stream>>>(ga);
    wtrans<<<dim3(24, 96), tb, 0, stream>>>(m_w2, Wq, 3072, 768);
    ga = GemmArgs{};
    ga.A[0] = hb; ga.BT[0] = Wq; ga.bias[0] = m_b2; ga.res[0] = R; ga.out[0] = out_x; ga.alpha[0] = 1.f;
    ga.M = 4096; ga.N = 768; ga.K = 3072;
    gemm_bt<1><<<dim3(32, 6, 1), tb, 0, stream>>>(ga);   // fp32 output

    (void)in_sizes; (void)n_in; (void)out_size;
}

// Round 8
// 466.619 us; speedup vs baseline: 1.1279x; 1.1279x over previous
//
#include <hip/hip_runtime.h>
#include <hip/hip_bf16.h>
#include <math.h>

#define CDIM 768
#define HDIM 3072
#define NROWS 4096   // B*T
#define TSEQ 2048
#define NHEAD 12

typedef unsigned short u16;
typedef unsigned int   u32;
typedef __attribute__((ext_vector_type(8))) short short8;
typedef __attribute__((ext_vector_type(4))) float f32x4;

// 1/sqrt(64) * log2(e): folds the softmax ln->log2 conversion into Q
#define QSCALE 0.18033688011112042f

static __device__ __forceinline__ u16 f2bf(float f) {
    u32 x = __float_as_uint(f);
    x += 0x7fffu + ((x >> 16) & 1u);
    return (u16)(x >> 16);
}

#define GLL16(g, l)                                                            \
    __builtin_amdgcn_global_load_lds(                                          \
        (const __attribute__((address_space(1))) void*)(g),                    \
        (__attribute__((address_space(3))) void*)(l), 16, 0, 0)

static __device__ __forceinline__ float redmax16(float v) {
#pragma unroll
    for (int m = 1; m < 16; m <<= 1) v = fmaxf(v, __shfl_xor(v, m));
    return v;
}
static __device__ __forceinline__ float redsum16(float v) {
#pragma unroll
    for (int m = 1; m < 16; m <<= 1) v += __shfl_xor(v, m);
    return v;
}

// ---------------------------------------------------------------- transpose
__launch_bounds__(256)
__global__ void wtrans(const float* __restrict__ w, u16* __restrict__ wt,
                       int K, int N) {
    __shared__ float t[32][33];
    const int n0 = blockIdx.x * 32, k0 = blockIdx.y * 32;
    const int tx = threadIdx.x & 31, ty = threadIdx.x >> 5;
#pragma unroll
    for (int i = ty; i < 32; i += 8)
        t[i][tx] = w[(size_t)(k0 + i) * N + n0 + tx];
    __syncthreads();
#pragma unroll
    for (int i = ty; i < 32; i += 8)
        wt[(size_t)(n0 + i) * K + k0 + tx] = f2bf(t[tx][i]);
}

// ---------------------------------------------------------------- fp32 -> bf16 copy
__launch_bounds__(256)
__global__ void cvt_copy(const float* __restrict__ in, u16* __restrict__ out,
                         int n4) {
    int i = blockIdx.x * 256 + threadIdx.x;
    if (i >= n4) return;
    float4 v = ((const float4*)in)[i];
    ushort4 o;
    o.x = f2bf(v.x); o.y = f2bf(v.y); o.z = f2bf(v.z); o.w = f2bf(v.w);
    ((ushort4*)out)[i] = o;
}

// ---------------------------------------------------------------- layernorm
__launch_bounds__(256)
__global__ void ln_kernel(const float* __restrict__ x, const float* __restrict__ g,
                          const float* __restrict__ bta, u16* __restrict__ out) {
    const int row = blockIdx.x, tid = threadIdx.x;
    const float* xr = x + (size_t)row * CDIM;
    float v0 = xr[tid], v1 = xr[tid + 256], v2 = xr[tid + 512];
    __shared__ float red[8];
    float s = v0 + v1 + v2;
#pragma unroll
    for (int m = 1; m < 64; m <<= 1) s += __shfl_xor(s, m);
    if ((tid & 63) == 0) red[tid >> 6] = s;
    __syncthreads();
    const float mu = (red[0] + red[1] + red[2] + red[3]) * (1.f / CDIM);
    const float d0 = v0 - mu, d1 = v1 - mu, d2 = v2 - mu;
    float q = d0 * d0 + d1 * d1 + d2 * d2;
#pragma unroll
    for (int m = 1; m < 64; m <<= 1) q += __shfl_xor(q, m);
    if ((tid & 63) == 0) red[4 + (tid >> 6)] = q;
    __syncthreads();
    const float var = (red[4] + red[5] + red[6] + red[7]) * (1.f / CDIM);
    const float rstd = rsqrtf(var + 1e-5f);
    u16* orow = out + (size_t)row * CDIM;
    orow[tid]       = f2bf(d0 * rstd * g[tid]       + bta[tid]);
    orow[tid + 256] = f2bf(d1 * rstd * g[tid + 256] + bta[tid + 256]);
    orow[tid + 512] = f2bf(d2 * rstd * g[tid + 512] + bta[tid + 512]);
}

// ---------------------------------------------------------------- GEMM
// C[M,N] = A[M,K](bf16) * BT[N,K]^T(bf16) + bias.
// BM x 128 tile, BK=32, 4 waves, global_load_lds staging (m97 structure).
// BM=64 variant for small-grid GEMMs (fills more CUs).
struct GemmArgs {
    const u16* A[3];
    const u16* BT[3];
    const float* bias[3];
    const float* res[3];
    void* out[3];
    float alpha[3];
    int M, N, K;
};

// EPI: 0 = (s+bias)*alpha -> bf16 ; 1 = res + s + bias -> f32 ;
//      2 = gelu(s+bias) -> bf16
template <int EPI, int BM>
__launch_bounds__(256)
__global__ void gemm_bt(GemmArgs ga) {
    constexpr int MF = BM / 32;           // A-frags per wave
    __shared__ u16 Abuf[BM * 32];
    __shared__ u16 Bbuf[128 * 32];
    const int z = blockIdx.z;
    const u16* __restrict__ A  = ga.A[z];
    const u16* __restrict__ BT = ga.BT[z];
    const float* __restrict__ bias = ga.bias[z];
    const float* __restrict__ res  = ga.res[z];
    void* outv = ga.out[z];
    const float alpha = ga.alpha[z];
    const int N = ga.N, K = ga.K;

    const int tid = threadIdx.x;
    const int lane = tid & 63, w = tid >> 6;
    const int m0 = blockIdx.x * BM, n0 = blockIdx.y * 128;
    const int wr = (w >> 1) * (BM / 2), wc = (w & 1) * 64;
    const int lr = lane & 15, lc = lane >> 4;

    const int srowA = w * (BM / 4) + (lane >> 2);
    const int srowB = w * 32 + (lane >> 2);
    const int scol = (lane & 3) * 8;
    const u16* Ag = A + (size_t)(m0 + srowA) * K + scol;
    const u16* Bg = BT + (size_t)(n0 + srowB) * K + scol;
    char* Ab = (char*)Abuf + w * (BM * 16);
    char* Bb = (char*)Bbuf + w * 2048;

    f32x4 acc[MF][4];
#pragma unroll
    for (int m = 0; m < MF; ++m)
#pragma unroll
        for (int n = 0; n < 4; ++n) acc[m][n] = (f32x4){0.f, 0.f, 0.f, 0.f};

    const int nk = K >> 5;
    for (int kt = 0; kt < nk; ++kt) {
        const int ko = kt * 32;
        GLL16(Ag + ko, Ab);
        if constexpr (BM == 128) GLL16(Ag + 16 * K + ko, Ab + 1024);
        GLL16(Bg + ko,          Bb);
        GLL16(Bg + 16 * K + ko, Bb + 1024);
        __syncthreads();
        short8 af[MF], bfv[4];
#pragma unroll
        for (int m = 0; m < MF; ++m)
            af[m] = *(const short8*)((const char*)Abuf +
                                     (size_t)(wr + m * 16 + lr) * 64 + lc * 16);
#pragma unroll
        for (int n = 0; n < 4; ++n)
            bfv[n] = *(const short8*)((const char*)Bbuf +
                                      (size_t)(wc + n * 16 + lr) * 64 + lc * 16);
#pragma unroll
        for (int m = 0; m < MF; ++m)
#pragma unroll
            for (int n = 0; n < 4; ++n)
                acc[m][n] = __builtin_amdgcn_mfma_f32_16x16x32_bf16(
                    af[m], bfv[n], acc[m][n], 0, 0, 0);
        __syncthreads();
    }

    // epilogue: C/D layout col=lane&15, row=(lane>>4)*4+reg
#pragma unroll
    for (int n = 0; n < 4; ++n) {
        const int gc = n0 + wc + n * 16 + lr;
        const float bs = bias[gc];
#pragma unroll
        for (int m = 0; m < MF; ++m) {
            const int gr = m0 + wr + m * 16 + lc * 4;
#pragma unroll
            for (int r = 0; r < 4; ++r) {
                float v = (acc[m][n][r] + bs) * alpha;
                const size_t idx = (size_t)(gr + r) * N + gc;
                if constexpr (EPI == 0) {
                    ((u16*)outv)[idx] = f2bf(v);
                } else if constexpr (EPI == 1) {
                    ((float*)outv)[idx] = res[idx] + v;
                } else {
                    float gel = 0.5f * v * (1.0f + erff(v * 0.70710678118654752f));
                    ((u16*)outv)[idx] = f2bf(gel);
                }
            }
        }
    }
}

// ---------------------------------------------------------------- attention
// Flash attention, 64 q-rows/block (4 waves x 16 rows), KBLK=64, dh=64.
// Q pre-scaled by QSCALE (1/8 * log2e) -> softmax in exp2 domain.
// V-tile stored transposed with XOR-swizzle (write col ^= stg_s<<5,
// read col ^= fd<<5) -> conflict-free transpose writes.
// K/V global loads for tile kt+1 prefetched into regs during compute of kt.
__launch_bounds__(256)
__global__ void attn_kernel(const u16* __restrict__ Qb, const u16* __restrict__ Kb,
                            const u16* __restrict__ Vb, u16* __restrict__ Ob) {
    __shared__ u16 Klds[64 * 72];      // K rows, stride 72 elems (144B)
    __shared__ u16 Vt[64 * 72];        // V transposed [d][k], swizzled
    __shared__ u16 Plds[4][16 * 72];   // per-wave P redistribution
    const int tid = threadIdx.x;
    const int lane = tid & 63, w = tid >> 6;
    const int lr = lane & 15, lc = lane >> 4;
    const int b = blockIdx.y / NHEAD, h = blockIdx.y % NHEAD;
    const size_t qrow0 = (size_t)b * TSEQ + blockIdx.x * 64 + w * 16;
    const size_t krow0 = (size_t)b * TSEQ;
    const int hc = h * 64;

    short8 qf0, qf1;
    {
        const u16* qp = Qb + (qrow0 + lr) * CDIM + hc + lc * 8;
        qf0 = *(const short8*)qp;
        qf1 = *(const short8*)(qp + 32);
    }
    f32x4 oacc[4];
    float mrow[4], lrow[4];
#pragma unroll
    for (int r = 0; r < 4; ++r) {
        oacc[r] = (f32x4){0.f, 0.f, 0.f, 0.f};
        mrow[r] = -3e38f;
        lrow[r] = 0.f;
    }

    const int stg_r = tid >> 2, stg_s = tid & 3;
    const u16* kg = Kb + (krow0 + stg_r) * CDIM + hc + stg_s * 16;
    const u16* vg = Vb + (krow0 + stg_r) * CDIM + hc + stg_s * 16;
    // prologue prefetch of tile 0
    uint4 ka0 = *(const uint4*)kg, ka1 = *(const uint4*)(kg + 8);
    uint4 va0 = *(const uint4*)vg, va1 = *(const uint4*)(vg + 8);
    // swizzled V write base: byte col = (stg_r*2) ^ (stg_s<<5), row = stg_s*16+j
    char* vdst = (char*)Vt + ((stg_r * 2) ^ (stg_s << 5)) +
                 (size_t)(stg_s * 16) * 144;

    for (int kt = 0; kt < TSEQ / 64; ++kt) {
        __syncthreads();   // previous tile's compute done; LDS reusable
        {   // write staged K (row-major) and V (transposed, swizzled)
            *(uint4*)&Klds[stg_r * 72 + stg_s * 16]     = ka0;
            *(uint4*)&Klds[stg_r * 72 + stg_s * 16 + 8] = ka1;
            u16 tmp[16];
            *(uint4*)(tmp)     = va0;
            *(uint4*)(tmp + 8) = va1;
#pragma unroll
            for (int j = 0; j < 16; ++j)
                *(u16*)(vdst + (size_t)j * 144) = tmp[j];
        }
        if (kt < TSEQ / 64 - 1) {   // prefetch next tile (lands during compute)
            kg += 64 * CDIM; vg += 64 * CDIM;
            ka0 = *(const uint4*)kg; ka1 = *(const uint4*)(kg + 8);
            va0 = *(const uint4*)vg; va1 = *(const uint4*)(vg + 8);
        }
        __syncthreads();

        // S = Q * K^T  (log2-domain scores; QSCALE folded into Q)
        f32x4 sf[4];
#pragma unroll
        for (int fn = 0; fn < 4; ++fn) {
            const u16* kr = &Klds[(lr + fn * 16) * 72 + lc * 8];
            short8 kb0 = *(const short8*)kr;
            short8 kb1 = *(const short8*)(kr + 32);
            f32x4 t = (f32x4){0.f, 0.f, 0.f, 0.f};
            t = __builtin_amdgcn_mfma_f32_16x16x32_bf16(qf0, kb0, t, 0, 0, 0);
            t = __builtin_amdgcn_mfma_f32_16x16x32_bf16(qf1, kb1, t, 0, 0, 0);
            sf[fn] = t;
        }

        // online softmax (row = (lane>>4)*4 + r, col = lane&15 + 16*fn)
#pragma unroll
        for (int r = 0; r < 4; ++r) {
            float pm = fmaxf(fmaxf(sf[0][r], sf[1][r]), fmaxf(sf[2][r], sf[3][r]));
            pm = redmax16(pm);
            const float mn = fmaxf(mrow[r], pm);
            const float corr = exp2f(mrow[r] - mn);
            mrow[r] = mn;
            float rs = 0.f;
#pragma unroll
            for (int fn = 0; fn < 4; ++fn) {
                float p = exp2f(sf[fn][r] - mn);
                sf[fn][r] = p;
                rs += p;
            }
            rs = redsum16(rs);
            lrow[r] = lrow[r] * corr + rs;
#pragma unroll
            for (int fd = 0; fd < 4; ++fd) oacc[fd][r] *= corr;
#pragma unroll
            for (int fn = 0; fn < 4; ++fn)
                Plds[w][(lc * 4 + r) * 72 + lr + fn * 16] = f2bf(sf[fn][r]);
        }
        asm volatile("s_waitcnt lgkmcnt(0)" ::: "memory");
        __builtin_amdgcn_sched_barrier(0);

        // O += P * V   (Vt reads use compile-time swizzle key fd<<5)
        short8 pa0 = *(const short8*)&Plds[w][lr * 72 + lc * 8];
        short8 pa1 = *(const short8*)&Plds[w][lr * 72 + lc * 8 + 32];
#pragma unroll
        for (int fd = 0; fd < 4; ++fd) {
            const char* vtb = (const char*)Vt + (size_t)(lr + fd * 16) * 144;
            short8 vb0 = *(const short8*)(vtb + ((lc * 16) ^ (fd * 32)));
            short8 vb1 = *(const short8*)(vtb + ((lc * 16 + 64) ^ (fd * 32)));
            oacc[fd] = __builtin_amdgcn_mfma_f32_16x16x32_bf16(pa0, vb0, oacc[fd], 0, 0, 0);
            oacc[fd] = __builtin_amdgcn_mfma_f32_16x16x32_bf16(pa1, vb1, oacc[fd], 0, 0, 0);
        }
    }

#pragma unroll
    for (int r = 0; r < 4; ++r) {
        const float rl = 1.f / lrow[r];
#pragma unroll
        for (int fd = 0; fd < 4; ++fd) {
            Ob[(qrow0 + lc * 4 + r) * CDIM + hc + fd * 16 + lr] =
                f2bf(oacc[fd][r] * rl);
        }
    }
}

// ---------------------------------------------------------------- launch
extern "C" void kernel_launch(void* const* d_in, const int* in_sizes, int n_in,
                              void* d_out, int out_size, void* d_ws, size_t ws_size,
                              hipStream_t stream) {
    const float* x     = (const float*)d_in[0];
    const float* ctx   = (const float*)d_in[1];
    const float* ln1g  = (const float*)d_in[2];
    const float* ln1b  = (const float*)d_in[3];
    const float* ln2g  = (const float*)d_in[4];
    const float* ln2b  = (const float*)d_in[5];
    const float* ln3g  = (const float*)d_in[6];
    const float* ln3b  = (const float*)d_in[7];
    const float* sa_wq = (const float*)d_in[8];
    const float* sa_bq = (const float*)d_in[9];
    const float* sa_wk = (const float*)d_in[10];
    const float* sa_bk = (const float*)d_in[11];
    const float* sa_wv = (const float*)d_in[12];
    const float* sa_bv = (const float*)d_in[13];
    const float* sa_wo = (const float*)d_in[14];
    const float* sa_bo = (const float*)d_in[15];
    const float* xa_wq = (const float*)d_in[16];
    const float* xa_bq = (const float*)d_in[17];
    const float* xa_wk = (const float*)d_in[18];
    const float* xa_bk = (const float*)d_in[19];
    const float* xa_wv = (const float*)d_in[20];
    const float* xa_bv = (const float*)d_in[21];
    const float* xa_wo = (const float*)d_in[22];
    const float* xa_bo = (const float*)d_in[23];
    const float* m_w1  = (const float*)d_in[24];
    const float* m_b1  = (const float*)d_in[25];
    const float* m_w2  = (const float*)d_in[26];
    const float* m_b2  = (const float*)d_in[27];

    // output is fp32: [x (4096x768), context (4096x768)]
    float* out_x   = (float*)d_out;
    float* out_ctx = out_x + (size_t)NROWS * CDIM;

    const size_t SZ_ACT  = (size_t)NROWS * CDIM * 2;
    const size_t SZ_WBIG = (size_t)HDIM * CDIM * 2;
    const size_t SZ_R    = (size_t)NROWS * CDIM * 4;
    const size_t NEEDED  = 5 * SZ_ACT + SZ_R + SZ_WBIG;
    if (ws_size < NEEDED) return;

    char* ws = (char*)d_ws;
    u16* qb    = (u16*)(ws);
    u16* kb    = (u16*)(ws + 1 * SZ_ACT);
    u16* vb    = (u16*)(ws + 2 * SZ_ACT);
    u16* ctxb  = (u16*)(ws + 3 * SZ_ACT);          // bf16 context (dead by MLP)
    u16* hb    = qb;                               // 4096x3072 bf16 = 4*SZ_ACT
    u16* lnbuf = (u16*)(ws + 4 * SZ_ACT);
    u16* attB  = lnbuf;                            // alias: disjoint lifetimes
    float* R   = (float*)(ws + 5 * SZ_ACT);
    u16* Wq    = (u16*)(ws + 5 * SZ_ACT + SZ_R);   // weight pool
    u16* Wk    = Wq + (size_t)CDIM * CDIM;
    u16* Wv    = Wk + (size_t)CDIM * CDIM;

    const dim3 tb(256);
    GemmArgs ga;

    hipMemcpyAsync(out_ctx, ctx, (size_t)NROWS * CDIM * 4,
                   hipMemcpyDeviceToDevice, stream);
    cvt_copy<<<dim3(3072), tb, 0, stream>>>(ctx, ctxb, NROWS * CDIM / 4);

    // ---- self-attention
    ln_kernel<<<dim3(NROWS), tb, 0, stream>>>(x, ln1g, ln1b, lnbuf);
    wtrans<<<dim3(24, 24), tb, 0, stream>>>(sa_wq, Wq, 768, 768);
    wtrans<<<dim3(24, 24), tb, 0, stream>>>(sa_wk, Wk, 768, 768);
    wtrans<<<dim3(24, 24), tb, 0, stream>>>(sa_wv, Wv, 768, 768);
    ga = GemmArgs{};
    ga.A[0] = lnbuf; ga.BT[0] = Wq; ga.bias[0] = sa_bq; ga.out[0] = qb; ga.alpha[0] = QSCALE;
    ga.A[1] = lnbuf; ga.BT[1] = Wk; ga.bias[1] = sa_bk; ga.out[1] = kb; ga.alpha[1] = 1.f;
    ga.A[2] = lnbuf; ga.BT[2] = Wv; ga.bias[2] = sa_bv; ga.out[2] = vb; ga.alpha[2] = 1.f;
    ga.M = 4096; ga.N = 768; ga.K = 768;
    gemm_bt<0, 128><<<dim3(32, 6, 3), tb, 0, stream>>>(ga);
    attn_kernel<<<dim3(32, 24), tb, 0, stream>>>(qb, kb, vb, attB);
    wtrans<<<dim3(24, 24), tb, 0, stream>>>(sa_wo, Wq, 768, 768);
    ga = GemmArgs{};
    ga.A[0] = attB; ga.BT[0] = Wq; ga.bias[0] = sa_bo; ga.res[0] = x; ga.out[0] = R; ga.alpha[0] = 1.f;
    ga.M = 4096; ga.N = 768; ga.K = 768;
    gemm_bt<1, 64><<<dim3(64, 6, 1), tb, 0, stream>>>(ga);

    // ---- cross-attention
    ln_kernel<<<dim3(NROWS), tb, 0, stream>>>(R, ln2g, ln2b, lnbuf);
    wtrans<<<dim3(24, 24), tb, 0, stream>>>(xa_wq, Wq, 768, 768);
    wtrans<<<dim3(24, 24), tb, 0, stream>>>(xa_wk, Wk, 768, 768);
    wtrans<<<dim3(24, 24), tb, 0, stream>>>(xa_wv, Wv, 768, 768);
    ga = GemmArgs{};
    ga.A[0] = lnbuf; ga.BT[0] = Wq; ga.bias[0] = xa_bq; ga.out[0] = qb; ga.alpha[0] = QSCALE;
    ga.A[1] = ctxb;  ga.BT[1] = Wk; ga.bias[1] = xa_bk; ga.out[1] = kb; ga.alpha[1] = 1.f;
    ga.A[2] = ctxb;  ga.BT[2] = Wv; ga.bias[2] = xa_bv; ga.out[2] = vb; ga.alpha[2] = 1.f;
    ga.M = 4096; ga.N = 768; ga.K = 768;
    gemm_bt<0, 128><<<dim3(32, 6, 3), tb, 0, stream>>>(ga);
    attn_kernel<<<dim3(32, 24), tb, 0, stream>>>(qb, kb, vb, attB);
    wtrans<<<dim3(24, 24), tb, 0, stream>>>(xa_wo, Wq, 768, 768);
    ga = GemmArgs{};
    ga.A[0] = attB; ga.BT[0] = Wq; ga.bias[0] = xa_bo; ga.res[0] = R; ga.out[0] = R; ga.alpha[0] = 1.f;
    ga.M = 4096; ga.N = 768; ga.K = 768;
    gemm_bt<1, 64><<<dim3(64, 6, 1), tb, 0, stream>>>(ga);

    // ---- MLP
    ln_kernel<<<dim3(NROWS), tb, 0, stream>>>(R, ln3g, ln3b, lnbuf);
    wtrans<<<dim3(96, 24), tb, 0, stream>>>(m_w1, Wq, 768, 3072);
    ga = GemmArgs{};
    ga.A[0] = lnbuf; ga.BT[0] = Wq; ga.bias[0] = m_b1; ga.out[0] = hb; ga.alpha[0] = 1.f;
    ga.M = 4096; ga.N = 3072; ga.K = 768;
    gemm_bt<2, 128><<<dim3(32, 24, 1), tb, 0, stream>>>(ga);
    wtrans<<<dim3(24, 96), tb, 0, stream>>>(m_w2, Wq, 3072, 768);
    ga = GemmArgs{};
    ga.A[0] = hb; ga.BT[0] = Wq; ga.bias[0] = m_b2; ga.res[0] = R; ga.out[0] = out_x; ga.alpha[0] = 1.f;
    ga.M = 4096; ga.N = 768; ga.K = 3072;
    gemm_bt<1, 64><<<dim3(64, 6, 1), tb, 0, stream>>>(ga);

    (void)in_sizes; (void)n_in; (void)out_size;
}

// Round 10
// 394.763 us; speedup vs baseline: 1.3332x; 1.1820x over previous
//
#include <hip/hip_runtime.h>
#include <hip/hip_bf16.h>
#include <math.h>

#define CDIM 768
#define HDIM 3072
#define NROWS 4096   // B*T
#define TSEQ 2048
#define NHEAD 12

typedef unsigned short u16;
typedef unsigned int   u32;
typedef __attribute__((ext_vector_type(8))) short short8;
typedef __attribute__((ext_vector_type(4))) float f32x4;

// 1/sqrt(64) * log2(e): folds the softmax ln->log2 conversion into Q
#define QSCALE 0.18033688011112042f

static __device__ __forceinline__ u16 f2bf(float f) {
    u32 x = __float_as_uint(f);
    x += 0x7fffu + ((x >> 16) & 1u);
    return (u16)(x >> 16);
}
static __device__ __forceinline__ u32 cvt_pk_bf16(float lo, float hi) {
    u32 r;
    asm("v_cvt_pk_bf16_f32 %0, %1, %2" : "=v"(r) : "v"(lo), "v"(hi));
    return r;
}

#define GLL16(g, l)                                                            \
    __builtin_amdgcn_global_load_lds(                                          \
        (const __attribute__((address_space(1))) void*)(g),                    \
        (__attribute__((address_space(3))) void*)(l), 16, 0, 0)

// ---------------------------------------------------------------- transpose
__launch_bounds__(256)
__global__ void wtrans(const float* __restrict__ w, u16* __restrict__ wt,
                       int K, int N) {
    __shared__ float t[32][33];
    const int n0 = blockIdx.x * 32, k0 = blockIdx.y * 32;
    const int tx = threadIdx.x & 31, ty = threadIdx.x >> 5;
#pragma unroll
    for (int i = ty; i < 32; i += 8)
        t[i][tx] = w[(size_t)(k0 + i) * N + n0 + tx];
    __syncthreads();
#pragma unroll
    for (int i = ty; i < 32; i += 8)
        wt[(size_t)(n0 + i) * K + k0 + tx] = f2bf(t[tx][i]);
}

// ---------------------------------------------------------------- fp32 -> bf16 copy
__launch_bounds__(256)
__global__ void cvt_copy(const float* __restrict__ in, u16* __restrict__ out,
                         int n4) {
    int i = blockIdx.x * 256 + threadIdx.x;
    if (i >= n4) return;
    float4 v = ((const float4*)in)[i];
    ushort4 o;
    o.x = f2bf(v.x); o.y = f2bf(v.y); o.z = f2bf(v.z); o.w = f2bf(v.w);
    ((ushort4*)out)[i] = o;
}

// ---------------------------------------------------------------- layernorm
__launch_bounds__(256)
__global__ void ln_kernel(const float* __restrict__ x, const float* __restrict__ g,
                          const float* __restrict__ bta, u16* __restrict__ out) {
    const int row = blockIdx.x, tid = threadIdx.x;
    const float* xr = x + (size_t)row * CDIM;
    float v0 = xr[tid], v1 = xr[tid + 256], v2 = xr[tid + 512];
    __shared__ float red[8];
    float s = v0 + v1 + v2;
#pragma unroll
    for (int m = 1; m < 64; m <<= 1) s += __shfl_xor(s, m);
    if ((tid & 63) == 0) red[tid >> 6] = s;
    __syncthreads();
    const float mu = (red[0] + red[1] + red[2] + red[3]) * (1.f / CDIM);
    const float d0 = v0 - mu, d1 = v1 - mu, d2 = v2 - mu;
    float q = d0 * d0 + d1 * d1 + d2 * d2;
#pragma unroll
    for (int m = 1; m < 64; m <<= 1) q += __shfl_xor(q, m);
    if ((tid & 63) == 0) red[4 + (tid >> 6)] = q;
    __syncthreads();
    const float var = (red[4] + red[5] + red[6] + red[7]) * (1.f / CDIM);
    const float rstd = rsqrtf(var + 1e-5f);
    u16* orow = out + (size_t)row * CDIM;
    orow[tid]       = f2bf(d0 * rstd * g[tid]       + bta[tid]);
    orow[tid + 256] = f2bf(d1 * rstd * g[tid + 256] + bta[tid + 256]);
    orow[tid + 512] = f2bf(d2 * rstd * g[tid + 512] + bta[tid + 512]);
}

// ---------------------------------------------------------------- GEMM (unchanged from R8)
struct GemmArgs {
    const u16* A[3];
    const u16* BT[3];
    const float* bias[3];
    const float* res[3];
    void* out[3];
    float alpha[3];
    int M, N, K;
};

// EPI: 0 = (s+bias)*alpha -> bf16 ; 1 = res + s + bias -> f32 ; 2 = gelu -> bf16
template <int EPI, int BM>
__launch_bounds__(256)
__global__ void gemm_bt(GemmArgs ga) {
    constexpr int MF = BM / 32;
    __shared__ u16 Abuf[BM * 32];
    __shared__ u16 Bbuf[128 * 32];
    const int z = blockIdx.z;
    const u16* __restrict__ A  = ga.A[z];
    const u16* __restrict__ BT = ga.BT[z];
    const float* __restrict__ bias = ga.bias[z];
    const float* __restrict__ res  = ga.res[z];
    void* outv = ga.out[z];
    const float alpha = ga.alpha[z];
    const int N = ga.N, K = ga.K;

    const int tid = threadIdx.x;
    const int lane = tid & 63, w = tid >> 6;
    const int m0 = blockIdx.x * BM, n0 = blockIdx.y * 128;
    const int wr = (w >> 1) * (BM / 2), wc = (w & 1) * 64;
    const int lr = lane & 15, lc = lane >> 4;

    const int srowA = w * (BM / 4) + (lane >> 2);
    const int srowB = w * 32 + (lane >> 2);
    const int scol = (lane & 3) * 8;
    const u16* Ag = A + (size_t)(m0 + srowA) * K + scol;
    const u16* Bg = BT + (size_t)(n0 + srowB) * K + scol;
    char* Ab = (char*)Abuf + w * (BM * 16);
    char* Bb = (char*)Bbuf + w * 2048;

    f32x4 acc[MF][4];
#pragma unroll
    for (int m = 0; m < MF; ++m)
#pragma unroll
        for (int n = 0; n < 4; ++n) acc[m][n] = (f32x4){0.f, 0.f, 0.f, 0.f};

    const int nk = K >> 5;
    for (int kt = 0; kt < nk; ++kt) {
        const int ko = kt * 32;
        GLL16(Ag + ko, Ab);
        if constexpr (BM == 128) GLL16(Ag + 16 * K + ko, Ab + 1024);
        GLL16(Bg + ko,          Bb);
        GLL16(Bg + 16 * K + ko, Bb + 1024);
        __syncthreads();
        short8 af[MF], bfv[4];
#pragma unroll
        for (int m = 0; m < MF; ++m)
            af[m] = *(const short8*)((const char*)Abuf +
                                     (size_t)(wr + m * 16 + lr) * 64 + lc * 16);
#pragma unroll
        for (int n = 0; n < 4; ++n)
            bfv[n] = *(const short8*)((const char*)Bbuf +
                                      (size_t)(wc + n * 16 + lr) * 64 + lc * 16);
#pragma unroll
        for (int m = 0; m < MF; ++m)
#pragma unroll
            for (int n = 0; n < 4; ++n)
                acc[m][n] = __builtin_amdgcn_mfma_f32_16x16x32_bf16(
                    af[m], bfv[n], acc[m][n], 0, 0, 0);
        __syncthreads();
    }

#pragma unroll
    for (int n = 0; n < 4; ++n) {
        const int gc = n0 + wc + n * 16 + lr;
        const float bs = bias[gc];
#pragma unroll
        for (int m = 0; m < MF; ++m) {
            const int gr = m0 + wr + m * 16 + lc * 4;
#pragma unroll
            for (int r = 0; r < 4; ++r) {
                float v = (acc[m][n][r] + bs) * alpha;
                const size_t idx = (size_t)(gr + r) * N + gc;
                if constexpr (EPI == 0) {
                    ((u16*)outv)[idx] = f2bf(v);
                } else if constexpr (EPI == 1) {
                    ((float*)outv)[idx] = res[idx] + v;
                } else {
                    float gel = 0.5f * v * (1.0f + erff(v * 0.70710678118654752f));
                    ((u16*)outv)[idx] = f2bf(gel);
                }
            }
        }
    }
}

// ---------------------------------------------------------------- attention
// Swapped-operand flash attention: S^T = mfma(K, Q) puts q in the C/D column
// -> lane (lr,lc) holds S[q=lr][k = 16*fn + 4*lc + r] : softmax is in-lane
// (tree reduce + 2 shuffles over the 4-lane q-group), P stays in registers.
// PV uses a k-PERMUTED V^T in LDS: Vt[d][sigma(k)] with
//   sigma(k) = 32*(k>>5) + 8*((k>>2)&3) + 4*((k>>4)&1) + (k&3)
// so the PV B-operand is 8 cvt_pk of the lane's own P values (no shuffles).
// O^T: lane holds O[q=lr][d = 16*fd + 4*lc + r]; packed ushort4 stores.
__launch_bounds__(256)
__global__ void attn_kernel(const u16* __restrict__ Qb, const u16* __restrict__ Kb,
                            const u16* __restrict__ Vb, u16* __restrict__ Ob) {
    __shared__ u16 Klds[64 * 72];      // K rows, stride 144B
    __shared__ u16 Vt[64 * 72];        // V^T, k-permuted + XOR-swizzled
    const int tid = threadIdx.x;
    const int lane = tid & 63, w = tid >> 6;
    const int lr = lane & 15, lc = lane >> 4;
    const int b = blockIdx.y / NHEAD, h = blockIdx.y % NHEAD;
    const size_t qrow0 = (size_t)b * TSEQ + blockIdx.x * 64 + w * 16;
    const size_t krow0 = (size_t)b * TSEQ;
    const int hc = h * 64;

    short8 qf0, qf1;
    {
        const u16* qp = Qb + (qrow0 + lr) * CDIM + hc + lc * 8;
        qf0 = *(const short8*)qp;
        qf1 = *(const short8*)(qp + 32);
    }
    f32x4 oacc[4];
#pragma unroll
    for (int r = 0; r < 4; ++r) oacc[r] = (f32x4){0.f, 0.f, 0.f, 0.f};
    float mrow = -3e38f, lrow = 0.f;

    const int stg_r = tid >> 2, stg_s = tid & 3;
    const u16* kg = Kb + (krow0 + stg_r) * CDIM + hc + stg_s * 16;
    const u16* vg = Vb + (krow0 + stg_r) * CDIM + hc + stg_s * 16;
    uint4 ka0 = *(const uint4*)kg, ka1 = *(const uint4*)(kg + 8);
    uint4 va0 = *(const uint4*)vg, va1 = *(const uint4*)(vg + 8);
    // permuted+swizzled V column for this thread's k = stg_r
    const int sig = ((stg_r >> 5) << 5) + (((stg_r >> 2) & 3) << 3) +
                    (((stg_r >> 4) & 1) << 2) + (stg_r & 3);
    char* vdst = (char*)Vt + ((2 * sig) ^ (stg_s << 5)) +
                 (size_t)(stg_s * 16) * 144;

    for (int kt = 0; kt < TSEQ / 64; ++kt) {
        __syncthreads();
        {   // write staged K (row-major) and V (transposed+permuted+swizzled)
            *(uint4*)&Klds[stg_r * 72 + stg_s * 16]     = ka0;
            *(uint4*)&Klds[stg_r * 72 + stg_s * 16 + 8] = ka1;
            u16 tmp[16];
            *(uint4*)(tmp)     = va0;
            *(uint4*)(tmp + 8) = va1;
#pragma unroll
            for (int j = 0; j < 16; ++j)
                *(u16*)(vdst + (size_t)j * 144) = tmp[j];
        }
        if (kt < TSEQ / 64 - 1) {   // prefetch next tile into regs
            kg += 64 * CDIM; vg += 64 * CDIM;
            ka0 = *(const uint4*)kg; ka1 = *(const uint4*)(kg + 8);
            va0 = *(const uint4*)vg; va1 = *(const uint4*)(vg + 8);
        }
        __syncthreads();

        // S^T = K * Q^T : sf[fn][r] = S[q=lr][k = 16*fn + 4*lc + r]
        f32x4 sf[4];
#pragma unroll
        for (int fn = 0; fn < 4; ++fn) {
            const u16* kr = &Klds[(lr + fn * 16) * 72 + lc * 8];
            short8 kb0 = *(const short8*)kr;
            short8 kb1 = *(const short8*)(kr + 32);
            f32x4 t = (f32x4){0.f, 0.f, 0.f, 0.f};
            t = __builtin_amdgcn_mfma_f32_16x16x32_bf16(kb0, qf0, t, 0, 0, 0);
            t = __builtin_amdgcn_mfma_f32_16x16x32_bf16(kb1, qf1, t, 0, 0, 0);
            sf[fn] = t;
        }

        // online softmax, in-lane (one q-row per lane, 4-lane group reduce)
        float pm;
        {
            float a0 = fmaxf(fmaxf(sf[0][0], sf[0][1]), fmaxf(sf[0][2], sf[0][3]));
            float a1 = fmaxf(fmaxf(sf[1][0], sf[1][1]), fmaxf(sf[1][2], sf[1][3]));
            float a2 = fmaxf(fmaxf(sf[2][0], sf[2][1]), fmaxf(sf[2][2], sf[2][3]));
            float a3 = fmaxf(fmaxf(sf[3][0], sf[3][1]), fmaxf(sf[3][2], sf[3][3]));
            pm = fmaxf(fmaxf(a0, a1), fmaxf(a2, a3));
            pm = fmaxf(pm, __shfl_xor(pm, 16));
            pm = fmaxf(pm, __shfl_xor(pm, 32));
        }
        const float mn = fmaxf(mrow, pm);
        const float corr = exp2f(mrow - mn);
        mrow = mn;
        float rs;
        {
#pragma unroll
            for (int fn = 0; fn < 4; ++fn)
#pragma unroll
                for (int r = 0; r < 4; ++r) sf[fn][r] = exp2f(sf[fn][r] - mn);
            float s0 = (sf[0][0] + sf[0][1]) + (sf[0][2] + sf[0][3]);
            float s1 = (sf[1][0] + sf[1][1]) + (sf[1][2] + sf[1][3]);
            float s2 = (sf[2][0] + sf[2][1]) + (sf[2][2] + sf[2][3]);
            float s3 = (sf[3][0] + sf[3][1]) + (sf[3][2] + sf[3][3]);
            rs = (s0 + s1) + (s2 + s3);
            rs += __shfl_xor(rs, 16);
            rs += __shfl_xor(rs, 32);
        }
        lrow = lrow * corr + rs;
#pragma unroll
        for (int fd = 0; fd < 4; ++fd)
#pragma unroll
            for (int r = 0; r < 4; ++r) oacc[fd][r] *= corr;

        // pack P in-register: B-operand slot s=8*lc+j -> own sf values
        int4 pw0, pw1;
        pw0.x = cvt_pk_bf16(sf[0][0], sf[0][1]);
        pw0.y = cvt_pk_bf16(sf[0][2], sf[0][3]);
        pw0.z = cvt_pk_bf16(sf[1][0], sf[1][1]);
        pw0.w = cvt_pk_bf16(sf[1][2], sf[1][3]);
        pw1.x = cvt_pk_bf16(sf[2][0], sf[2][1]);
        pw1.y = cvt_pk_bf16(sf[2][2], sf[2][3]);
        pw1.z = cvt_pk_bf16(sf[3][0], sf[3][1]);
        pw1.w = cvt_pk_bf16(sf[3][2], sf[3][3]);
        short8 pb0 = *(short8*)&pw0;
        short8 pb1 = *(short8*)&pw1;

        // O^T += V^T * P^T  (Vt is k-permuted to match the register P order)
#pragma unroll
        for (int fd = 0; fd < 4; ++fd) {
            const char* vtb = (const char*)Vt + (size_t)(lr + fd * 16) * 144;
            short8 vb0 = *(const short8*)(vtb + ((lc * 16) ^ (fd * 32)));
            short8 vb1 = *(const short8*)(vtb + ((lc * 16 + 64) ^ (fd * 32)));
            oacc[fd] = __builtin_amdgcn_mfma_f32_16x16x32_bf16(vb0, pb0, oacc[fd], 0, 0, 0);
            oacc[fd] = __builtin_amdgcn_mfma_f32_16x16x32_bf16(vb1, pb1, oacc[fd], 0, 0, 0);
        }
    }

    // epilogue: lane holds O[q=lr][d = 16*fd + 4*lc + r]; pack 4 -> 8B store
    const float rl = 1.f / lrow;
    u16* obase = Ob + (qrow0 + lr) * CDIM + hc + lc * 4;
#pragma unroll
    for (int fd = 0; fd < 4; ++fd) {
        ushort4 o;
        o.x = f2bf(oacc[fd][0] * rl);
        o.y = f2bf(oacc[fd][1] * rl);
        o.z = f2bf(oacc[fd][2] * rl);
        o.w = f2bf(oacc[fd][3] * rl);
        *(ushort4*)(obase + fd * 16) = o;
    }
}

// ---------------------------------------------------------------- launch
extern "C" void kernel_launch(void* const* d_in, const int* in_sizes, int n_in,
                              void* d_out, int out_size, void* d_ws, size_t ws_size,
                              hipStream_t stream) {
    const float* x     = (const float*)d_in[0];
    const float* ctx   = (const float*)d_in[1];
    const float* ln1g  = (const float*)d_in[2];
    const float* ln1b  = (const float*)d_in[3];
    const float* ln2g  = (const float*)d_in[4];
    const float* ln2b  = (const float*)d_in[5];
    const float* ln3g  = (const float*)d_in[6];
    const float* ln3b  = (const float*)d_in[7];
    const float* sa_wq = (const float*)d_in[8];
    const float* sa_bq = (const float*)d_in[9];
    const float* sa_wk = (const float*)d_in[10];
    const float* sa_bk = (const float*)d_in[11];
    const float* sa_wv = (const float*)d_in[12];
    const float* sa_bv = (const float*)d_in[13];
    const float* sa_wo = (const float*)d_in[14];
    const float* sa_bo = (const float*)d_in[15];
    const float* xa_wq = (const float*)d_in[16];
    const float* xa_bq = (const float*)d_in[17];
    const float* xa_wk = (const float*)d_in[18];
    const float* xa_bk = (const float*)d_in[19];
    const float* xa_wv = (const float*)d_in[20];
    const float* xa_bv = (const float*)d_in[21];
    const float* xa_wo = (const float*)d_in[22];
    const float* xa_bo = (const float*)d_in[23];
    const float* m_w1  = (const float*)d_in[24];
    const float* m_b1  = (const float*)d_in[25];
    const float* m_w2  = (const float*)d_in[26];
    const float* m_b2  = (const float*)d_in[27];

    float* out_x   = (float*)d_out;
    float* out_ctx = out_x + (size_t)NROWS * CDIM;

    const size_t SZ_ACT  = (size_t)NROWS * CDIM * 2;
    const size_t SZ_WBIG = (size_t)HDIM * CDIM * 2;
    const size_t SZ_R    = (size_t)NROWS * CDIM * 4;
    const size_t NEEDED  = 5 * SZ_ACT + SZ_R + SZ_WBIG;
    if (ws_size < NEEDED) return;

    char* ws = (char*)d_ws;
    u16* qb    = (u16*)(ws);
    u16* kb    = (u16*)(ws + 1 * SZ_ACT);
    u16* vb    = (u16*)(ws + 2 * SZ_ACT);
    u16* ctxb  = (u16*)(ws + 3 * SZ_ACT);
    u16* hb    = qb;
    u16* lnbuf = (u16*)(ws + 4 * SZ_ACT);
    u16* attB  = lnbuf;
    float* R   = (float*)(ws + 5 * SZ_ACT);
    u16* Wq    = (u16*)(ws + 5 * SZ_ACT + SZ_R);
    u16* Wk    = Wq + (size_t)CDIM * CDIM;
    u16* Wv    = Wk + (size_t)CDIM * CDIM;

    const dim3 tb(256);
    GemmArgs ga;

    hipMemcpyAsync(out_ctx, ctx, (size_t)NROWS * CDIM * 4,
                   hipMemcpyDeviceToDevice, stream);
    cvt_copy<<<dim3(3072), tb, 0, stream>>>(ctx, ctxb, NROWS * CDIM / 4);

    // ---- self-attention
    ln_kernel<<<dim3(NROWS), tb, 0, stream>>>(x, ln1g, ln1b, lnbuf);
    wtrans<<<dim3(24, 24), tb, 0, stream>>>(sa_wq, Wq, 768, 768);
    wtrans<<<dim3(24, 24), tb, 0, stream>>>(sa_wk, Wk, 768, 768);
    wtrans<<<dim3(24, 24), tb, 0, stream>>>(sa_wv, Wv, 768, 768);
    ga = GemmArgs{};
    ga.A[0] = lnbuf; ga.BT[0] = Wq; ga.bias[0] = sa_bq; ga.out[0] = qb; ga.alpha[0] = QSCALE;
    ga.A[1] = lnbuf; ga.BT[1] = Wk; ga.bias[1] = sa_bk; ga.out[1] = kb; ga.alpha[1] = 1.f;
    ga.A[2] = lnbuf; ga.BT[2] = Wv; ga.bias[2] = sa_bv; ga.out[2] = vb; ga.alpha[2] = 1.f;
    ga.M = 4096; ga.N = 768; ga.K = 768;
    gemm_bt<0, 128><<<dim3(32, 6, 3), tb, 0, stream>>>(ga);
    attn_kernel<<<dim3(32, 24), tb, 0, stream>>>(qb, kb, vb, attB);
    wtrans<<<dim3(24, 24), tb, 0, stream>>>(sa_wo, Wq, 768, 768);
    ga = GemmArgs{};
    ga.A[0] = attB; ga.BT[0] = Wq; ga.bias[0] = sa_bo; ga.res[0] = x; ga.out[0] = R; ga.alpha[0] = 1.f;
    ga.M = 4096; ga.N = 768; ga.K = 768;
    gemm_bt<1, 64><<<dim3(64, 6, 1), tb, 0, stream>>>(ga);

    // ---- cross-attention
    ln_kernel<<<dim3(NROWS), tb, 0, stream>>>(R, ln2g, ln2b, lnbuf);
    wtrans<<<dim3(24, 24), tb, 0, stream>>>(xa_wq, Wq, 768, 768);
    wtrans<<<dim3(24, 24), tb, 0, stream>>>(xa_wk, Wk, 768, 768);
    wtrans<<<dim3(24, 24), tb, 0, stream>>>(xa_wv, Wv, 768, 768);
    ga = GemmArgs{};
    ga.A[0] = lnbuf; ga.BT[0] = Wq; ga.bias[0] = xa_bq; ga.out[0] = qb; ga.alpha[0] = QSCALE;
    ga.A[1] = ctxb;  ga.BT[1] = Wk; ga.bias[1] = xa_bk; ga.out[1] = kb; ga.alpha[1] = 1.f;
    ga.A[2] = ctxb;  ga.BT[2] = Wv; ga.bias[2] = xa_bv; ga.out[2] = vb; ga.alpha[2] = 1.f;
    ga.M = 4096; ga.N = 768; ga.K = 768;
    gemm_bt<0, 128><<<dim3(32, 6, 3), tb, 0, stream>>>(ga);
    attn_kernel<<<dim3(32, 24), tb, 0, stream>>>(qb, kb, vb, attB);
    wtrans<<<dim3(24, 24), tb, 0, stream>>>(xa_wo, Wq, 768, 768);
    ga = GemmArgs{};
    ga.A[0] = attB; ga.BT[0] = Wq; ga.bias[0] = xa_bo; ga.res[0] = R; ga.out[0] = R; ga.alpha[0] = 1.f;
    ga.M = 4096; ga.N = 768; ga.K = 768;
    gemm_bt<1, 64><<<dim3(64, 6, 1), tb, 0, stream>>>(ga);

    // ---- MLP
    ln_kernel<<<dim3(NROWS), tb, 0, stream>>>(R, ln3g, ln3b, lnbuf);
    wtrans<<<dim3(96, 24), tb, 0, stream>>>(m_w1, Wq, 768, 3072);
    ga = GemmArgs{};
    ga.A[0] = lnbuf; ga.BT[0] = Wq; ga.bias[0] = m_b1; ga.out[0] = hb; ga.alpha[0] = 1.f;
    ga.M = 4096; ga.N = 3072; ga.K = 768;
    gemm_bt<2, 128><<<dim3(32, 24, 1), tb, 0, stream>>>(ga);
    wtrans<<<dim3(24, 96), tb, 0, stream>>>(m_w2, Wq, 3072, 768);
    ga = GemmArgs{};
    ga.A[0] = hb; ga.BT[0] = Wq; ga.bias[0] = m_b2; ga.res[0] = R; ga.out[0] = out_x; ga.alpha[0] = 1.f;
    ga.M = 4096; ga.N = 768; ga.K = 3072;
    gemm_bt<1, 64><<<dim3(64, 6, 1), tb, 0, stream>>>(ga);

    (void)in_sizes; (void)n_in; (void)out_size;
}

// Round 11
// 392.427 us; speedup vs baseline: 1.3412x; 1.0060x over previous
//
#include <hip/hip_runtime.h>
#include <hip/hip_bf16.h>
#include <math.h>

#define CDIM 768
#define HDIM 3072
#define NROWS 4096   // B*T
#define TSEQ 2048
#define NHEAD 12
#define KVSPLIT 2
#define KVLEN (TSEQ / KVSPLIT)   // 1024 rows per part

typedef unsigned short u16;
typedef unsigned int   u32;
typedef __attribute__((ext_vector_type(8))) short short8;
typedef __attribute__((ext_vector_type(4))) float f32x4;

// 1/sqrt(64) * log2(e): folds the softmax ln->log2 conversion into Q
#define QSCALE 0.18033688011112042f

static __device__ __forceinline__ u16 f2bf(float f) {
    u32 x = __float_as_uint(f);
    x += 0x7fffu + ((x >> 16) & 1u);
    return (u16)(x >> 16);
}
static __device__ __forceinline__ u32 cvt_pk_bf16(float lo, float hi) {
    u32 r;
    asm("v_cvt_pk_bf16_f32 %0, %1, %2" : "=v"(r) : "v"(lo), "v"(hi));
    return r;
}

#define GLL16(g, l)                                                            \
    __builtin_amdgcn_global_load_lds(                                          \
        (const __attribute__((address_space(1))) void*)(g),                    \
        (__attribute__((address_space(3))) void*)(l), 16, 0, 0)

// ---------------------------------------------------------------- transpose
__launch_bounds__(256)
__global__ void wtrans(const float* __restrict__ w, u16* __restrict__ wt,
                       int K, int N) {
    __shared__ float t[32][33];
    const int n0 = blockIdx.x * 32, k0 = blockIdx.y * 32;
    const int tx = threadIdx.x & 31, ty = threadIdx.x >> 5;
#pragma unroll
    for (int i = ty; i < 32; i += 8)
        t[i][tx] = w[(size_t)(k0 + i) * N + n0 + tx];
    __syncthreads();
#pragma unroll
    for (int i = ty; i < 32; i += 8)
        wt[(size_t)(n0 + i) * K + k0 + tx] = f2bf(t[tx][i]);
}

// ---------------------------------------------------------------- fp32 -> bf16 copy
__launch_bounds__(256)
__global__ void cvt_copy(const float* __restrict__ in, u16* __restrict__ out,
                         int n4) {
    int i = blockIdx.x * 256 + threadIdx.x;
    if (i >= n4) return;
    float4 v = ((const float4*)in)[i];
    ushort4 o;
    o.x = f2bf(v.x); o.y = f2bf(v.y); o.z = f2bf(v.z); o.w = f2bf(v.w);
    ((ushort4*)out)[i] = o;
}

// ---------------------------------------------------------------- layernorm
__launch_bounds__(256)
__global__ void ln_kernel(const float* __restrict__ x, const float* __restrict__ g,
                          const float* __restrict__ bta, u16* __restrict__ out) {
    const int row = blockIdx.x, tid = threadIdx.x;
    const float* xr = x + (size_t)row * CDIM;
    float v0 = xr[tid], v1 = xr[tid + 256], v2 = xr[tid + 512];
    __shared__ float red[8];
    float s = v0 + v1 + v2;
#pragma unroll
    for (int m = 1; m < 64; m <<= 1) s += __shfl_xor(s, m);
    if ((tid & 63) == 0) red[tid >> 6] = s;
    __syncthreads();
    const float mu = (red[0] + red[1] + red[2] + red[3]) * (1.f / CDIM);
    const float d0 = v0 - mu, d1 = v1 - mu, d2 = v2 - mu;
    float q = d0 * d0 + d1 * d1 + d2 * d2;
#pragma unroll
    for (int m = 1; m < 64; m <<= 1) q += __shfl_xor(q, m);
    if ((tid & 63) == 0) red[4 + (tid >> 6)] = q;
    __syncthreads();
    const float var = (red[4] + red[5] + red[6] + red[7]) * (1.f / CDIM);
    const float rstd = rsqrtf(var + 1e-5f);
    u16* orow = out + (size_t)row * CDIM;
    orow[tid]       = f2bf(d0 * rstd * g[tid]       + bta[tid]);
    orow[tid + 256] = f2bf(d1 * rstd * g[tid + 256] + bta[tid + 256]);
    orow[tid + 512] = f2bf(d2 * rstd * g[tid + 512] + bta[tid + 512]);
}

// ---------------------------------------------------------------- GEMM (unchanged)
struct GemmArgs {
    const u16* A[3];
    const u16* BT[3];
    const float* bias[3];
    const float* res[3];
    void* out[3];
    float alpha[3];
    int M, N, K;
};

// EPI: 0 = (s+bias)*alpha -> bf16 ; 1 = res + s + bias -> f32 ; 2 = gelu -> bf16
template <int EPI, int BM>
__launch_bounds__(256)
__global__ void gemm_bt(GemmArgs ga) {
    constexpr int MF = BM / 32;
    __shared__ u16 Abuf[BM * 32];
    __shared__ u16 Bbuf[128 * 32];
    const int z = blockIdx.z;
    const u16* __restrict__ A  = ga.A[z];
    const u16* __restrict__ BT = ga.BT[z];
    const float* __restrict__ bias = ga.bias[z];
    const float* __restrict__ res  = ga.res[z];
    void* outv = ga.out[z];
    const float alpha = ga.alpha[z];
    const int N = ga.N, K = ga.K;

    const int tid = threadIdx.x;
    const int lane = tid & 63, w = tid >> 6;
    const int m0 = blockIdx.x * BM, n0 = blockIdx.y * 128;
    const int wr = (w >> 1) * (BM / 2), wc = (w & 1) * 64;
    const int lr = lane & 15, lc = lane >> 4;

    const int srowA = w * (BM / 4) + (lane >> 2);
    const int srowB = w * 32 + (lane >> 2);
    const int scol = (lane & 3) * 8;
    const u16* Ag = A + (size_t)(m0 + srowA) * K + scol;
    const u16* Bg = BT + (size_t)(n0 + srowB) * K + scol;
    char* Ab = (char*)Abuf + w * (BM * 16);
    char* Bb = (char*)Bbuf + w * 2048;

    f32x4 acc[MF][4];
#pragma unroll
    for (int m = 0; m < MF; ++m)
#pragma unroll
        for (int n = 0; n < 4; ++n) acc[m][n] = (f32x4){0.f, 0.f, 0.f, 0.f};

    const int nk = K >> 5;
    for (int kt = 0; kt < nk; ++kt) {
        const int ko = kt * 32;
        GLL16(Ag + ko, Ab);
        if constexpr (BM == 128) GLL16(Ag + 16 * K + ko, Ab + 1024);
        GLL16(Bg + ko,          Bb);
        GLL16(Bg + 16 * K + ko, Bb + 1024);
        __syncthreads();
        short8 af[MF], bfv[4];
#pragma unroll
        for (int m = 0; m < MF; ++m)
            af[m] = *(const short8*)((const char*)Abuf +
                                     (size_t)(wr + m * 16 + lr) * 64 + lc * 16);
#pragma unroll
        for (int n = 0; n < 4; ++n)
            bfv[n] = *(const short8*)((const char*)Bbuf +
                                      (size_t)(wc + n * 16 + lr) * 64 + lc * 16);
#pragma unroll
        for (int m = 0; m < MF; ++m)
#pragma unroll
            for (int n = 0; n < 4; ++n)
                acc[m][n] = __builtin_amdgcn_mfma_f32_16x16x32_bf16(
                    af[m], bfv[n], acc[m][n], 0, 0, 0);
        __syncthreads();
    }

#pragma unroll
    for (int n = 0; n < 4; ++n) {
        const int gc = n0 + wc + n * 16 + lr;
        const float bs = bias[gc];
#pragma unroll
        for (int m = 0; m < MF; ++m) {
            const int gr = m0 + wr + m * 16 + lc * 4;
#pragma unroll
            for (int r = 0; r < 4; ++r) {
                float v = (acc[m][n][r] + bs) * alpha;
                const size_t idx = (size_t)(gr + r) * N + gc;
                if constexpr (EPI == 0) {
                    ((u16*)outv)[idx] = f2bf(v);
                } else if constexpr (EPI == 1) {
                    ((float*)outv)[idx] = res[idx] + v;
                } else {
                    float gel = 0.5f * v * (1.0f + erff(v * 0.70710678118654752f));
                    ((u16*)outv)[idx] = f2bf(gel);
                }
            }
        }
    }
}

// ---------------------------------------------------------------- attention (split-KV)
// Same swapped-operand inner loop as R10 (verified). gridDim.z = KVSPLIT parts;
// each part covers KVLEN kv-rows and writes UNNORMALIZED O-partials (f32) plus
// per-(row,head) (m, l) as float2. A merge kernel combines the parts.
__launch_bounds__(256)
__global__ void attn_split(const u16* __restrict__ Qb, const u16* __restrict__ Kb,
                           const u16* __restrict__ Vb, float* __restrict__ Opart,
                           float2* __restrict__ ml) {
    __shared__ u16 Klds[64 * 72];
    __shared__ u16 Vt[64 * 72];
    const int tid = threadIdx.x;
    const int lane = tid & 63, w = tid >> 6;
    const int lr = lane & 15, lc = lane >> 4;
    const int b = blockIdx.y / NHEAD, h = blockIdx.y % NHEAD;
    const int z = blockIdx.z;
    const size_t qrow0 = (size_t)b * TSEQ + blockIdx.x * 64 + w * 16;
    const size_t krow0 = (size_t)b * TSEQ + (size_t)z * KVLEN;
    const int hc = h * 64;

    short8 qf0, qf1;
    {
        const u16* qp = Qb + (qrow0 + lr) * CDIM + hc + lc * 8;
        qf0 = *(const short8*)qp;
        qf1 = *(const short8*)(qp + 32);
    }
    f32x4 oacc[4];
#pragma unroll
    for (int r = 0; r < 4; ++r) oacc[r] = (f32x4){0.f, 0.f, 0.f, 0.f};
    float mrow = -3e38f, lrow = 0.f;

    const int stg_r = tid >> 2, stg_s = tid & 3;
    const u16* kg = Kb + (krow0 + stg_r) * CDIM + hc + stg_s * 16;
    const u16* vg = Vb + (krow0 + stg_r) * CDIM + hc + stg_s * 16;
    uint4 ka0 = *(const uint4*)kg, ka1 = *(const uint4*)(kg + 8);
    uint4 va0 = *(const uint4*)vg, va1 = *(const uint4*)(vg + 8);
    const int sig = ((stg_r >> 5) << 5) + (((stg_r >> 2) & 3) << 3) +
                    (((stg_r >> 4) & 1) << 2) + (stg_r & 3);
    char* vdst = (char*)Vt + ((2 * sig) ^ (stg_s << 5)) +
                 (size_t)(stg_s * 16) * 144;

    for (int kt = 0; kt < KVLEN / 64; ++kt) {
        __syncthreads();
        {
            *(uint4*)&Klds[stg_r * 72 + stg_s * 16]     = ka0;
            *(uint4*)&Klds[stg_r * 72 + stg_s * 16 + 8] = ka1;
            u16 tmp[16];
            *(uint4*)(tmp)     = va0;
            *(uint4*)(tmp + 8) = va1;
#pragma unroll
            for (int j = 0; j < 16; ++j)
                *(u16*)(vdst + (size_t)j * 144) = tmp[j];
        }
        if (kt < KVLEN / 64 - 1) {
            kg += 64 * CDIM; vg += 64 * CDIM;
            ka0 = *(const uint4*)kg; ka1 = *(const uint4*)(kg + 8);
            va0 = *(const uint4*)vg; va1 = *(const uint4*)(vg + 8);
        }
        __syncthreads();

        // S^T = K * Q^T : sf[fn][r] = S[q=lr][k = 16*fn + 4*lc + r]
        f32x4 sf[4];
#pragma unroll
        for (int fn = 0; fn < 4; ++fn) {
            const u16* kr = &Klds[(lr + fn * 16) * 72 + lc * 8];
            short8 kb0 = *(const short8*)kr;
            short8 kb1 = *(const short8*)(kr + 32);
            f32x4 t = (f32x4){0.f, 0.f, 0.f, 0.f};
            t = __builtin_amdgcn_mfma_f32_16x16x32_bf16(kb0, qf0, t, 0, 0, 0);
            t = __builtin_amdgcn_mfma_f32_16x16x32_bf16(kb1, qf1, t, 0, 0, 0);
            sf[fn] = t;
        }

        // online softmax, in-lane (one q-row per lane, 4-lane group reduce)
        float pm;
        {
            float a0 = fmaxf(fmaxf(sf[0][0], sf[0][1]), fmaxf(sf[0][2], sf[0][3]));
            float a1 = fmaxf(fmaxf(sf[1][0], sf[1][1]), fmaxf(sf[1][2], sf[1][3]));
            float a2 = fmaxf(fmaxf(sf[2][0], sf[2][1]), fmaxf(sf[2][2], sf[2][3]));
            float a3 = fmaxf(fmaxf(sf[3][0], sf[3][1]), fmaxf(sf[3][2], sf[3][3]));
            pm = fmaxf(fmaxf(a0, a1), fmaxf(a2, a3));
            pm = fmaxf(pm, __shfl_xor(pm, 16));
            pm = fmaxf(pm, __shfl_xor(pm, 32));
        }
        const float mn = fmaxf(mrow, pm);
        const float corr = exp2f(mrow - mn);
        mrow = mn;
        float rs;
        {
#pragma unroll
            for (int fn = 0; fn < 4; ++fn)
#pragma unroll
                for (int r = 0; r < 4; ++r) sf[fn][r] = exp2f(sf[fn][r] - mn);
            float s0 = (sf[0][0] + sf[0][1]) + (sf[0][2] + sf[0][3]);
            float s1 = (sf[1][0] + sf[1][1]) + (sf[1][2] + sf[1][3]);
            float s2 = (sf[2][0] + sf[2][1]) + (sf[2][2] + sf[2][3]);
            float s3 = (sf[3][0] + sf[3][1]) + (sf[3][2] + sf[3][3]);
            rs = (s0 + s1) + (s2 + s3);
            rs += __shfl_xor(rs, 16);
            rs += __shfl_xor(rs, 32);
        }
        lrow = lrow * corr + rs;
#pragma unroll
        for (int fd = 0; fd < 4; ++fd)
#pragma unroll
            for (int r = 0; r < 4; ++r) oacc[fd][r] *= corr;

        int4 pw0, pw1;
        pw0.x = cvt_pk_bf16(sf[0][0], sf[0][1]);
        pw0.y = cvt_pk_bf16(sf[0][2], sf[0][3]);
        pw0.z = cvt_pk_bf16(sf[1][0], sf[1][1]);
        pw0.w = cvt_pk_bf16(sf[1][2], sf[1][3]);
        pw1.x = cvt_pk_bf16(sf[2][0], sf[2][1]);
        pw1.y = cvt_pk_bf16(sf[2][2], sf[2][3]);
        pw1.z = cvt_pk_bf16(sf[3][0], sf[3][1]);
        pw1.w = cvt_pk_bf16(sf[3][2], sf[3][3]);
        short8 pb0 = *(short8*)&pw0;
        short8 pb1 = *(short8*)&pw1;

#pragma unroll
        for (int fd = 0; fd < 4; ++fd) {
            const char* vtb = (const char*)Vt + (size_t)(lr + fd * 16) * 144;
            short8 vb0 = *(const short8*)(vtb + ((lc * 16) ^ (fd * 32)));
            short8 vb1 = *(const short8*)(vtb + ((lc * 16 + 64) ^ (fd * 32)));
            oacc[fd] = __builtin_amdgcn_mfma_f32_16x16x32_bf16(vb0, pb0, oacc[fd], 0, 0, 0);
            oacc[fd] = __builtin_amdgcn_mfma_f32_16x16x32_bf16(vb1, pb1, oacc[fd], 0, 0, 0);
        }
    }

    // epilogue: UNNORMALIZED f32 partial + (m,l).  Lane holds
    // O[q=lr][d = 16*fd + 4*lc + r]; m/l uniform across the 4 lanes of a q-row.
    float* obase = Opart + (size_t)z * NROWS * CDIM + (qrow0 + lr) * CDIM + hc + lc * 4;
#pragma unroll
    for (int fd = 0; fd < 4; ++fd) {
        float4 o = {oacc[fd][0], oacc[fd][1], oacc[fd][2], oacc[fd][3]};
        *(float4*)(obase + fd * 16) = o;
    }
    if (lc == 0)
        ml[((size_t)z * NROWS + qrow0 + lr) * NHEAD + h] = (float2){mrow, lrow};
}

// ---------------------------------------------------------------- merge of split-KV partials
__launch_bounds__(256)
__global__ void attn_merge(const float* __restrict__ P0, const float* __restrict__ P1,
                           const float2* __restrict__ ml, u16* __restrict__ out) {
    const int i4 = blockIdx.x * 256 + threadIdx.x;   // float4 index
    const size_t base = (size_t)i4 * 4;
    const int row = (int)(base / CDIM);
    const int head = (int)(base - (size_t)row * CDIM) >> 6;
    const float2 a = ml[(size_t)row * NHEAD + head];
    const float2 c = ml[((size_t)NROWS + row) * NHEAD + head];
    const float M = fmaxf(a.x, c.x);
    const float e0 = exp2f(a.x - M), e1 = exp2f(c.x - M);
    const float rden = 1.f / (a.y * e0 + c.y * e1);
    const float4 p0 = *(const float4*)(P0 + base);
    const float4 p1 = *(const float4*)(P1 + base);
    ushort4 o;
    o.x = f2bf((p0.x * e0 + p1.x * e1) * rden);
    o.y = f2bf((p0.y * e0 + p1.y * e1) * rden);
    o.z = f2bf((p0.z * e0 + p1.z * e1) * rden);
    o.w = f2bf((p0.w * e0 + p1.w * e1) * rden);
    *(ushort4*)(out + base) = o;
}

// ---------------------------------------------------------------- launch
extern "C" void kernel_launch(void* const* d_in, const int* in_sizes, int n_in,
                              void* d_out, int out_size, void* d_ws, size_t ws_size,
                              hipStream_t stream) {
    const float* x     = (const float*)d_in[0];
    const float* ctx   = (const float*)d_in[1];
    const float* ln1g  = (const float*)d_in[2];
    const float* ln1b  = (const float*)d_in[3];
    const float* ln2g  = (const float*)d_in[4];
    const float* ln2b  = (const float*)d_in[5];
    const float* ln3g  = (const float*)d_in[6];
    const float* ln3b  = (const float*)d_in[7];
    const float* sa_wq = (const float*)d_in[8];
    const float* sa_bq = (const float*)d_in[9];
    const float* sa_wk = (const float*)d_in[10];
    const float* sa_bk = (const float*)d_in[11];
    const float* sa_wv = (const float*)d_in[12];
    const float* sa_bv = (const float*)d_in[13];
    const float* sa_wo = (const float*)d_in[14];
    const float* sa_bo = (const float*)d_in[15];
    const float* xa_wq = (const float*)d_in[16];
    const float* xa_bq = (const float*)d_in[17];
    const float* xa_wk = (const float*)d_in[18];
    const float* xa_bk = (const float*)d_in[19];
    const float* xa_wv = (const float*)d_in[20];
    const float* xa_bv = (const float*)d_in[21];
    const float* xa_wo = (const float*)d_in[22];
    const float* xa_bo = (const float*)d_in[23];
    const float* m_w1  = (const float*)d_in[24];
    const float* m_b1  = (const float*)d_in[25];
    const float* m_w2  = (const float*)d_in[26];
    const float* m_b2  = (const float*)d_in[27];

    float* out_x   = (float*)d_out;
    float* out_ctx = out_x + (size_t)NROWS * CDIM;
    // d_out doubles as split-KV partial scratch until the final writes:
    float* Opart   = (float*)d_out;   // z=0 -> out_x area, z=1 -> out_ctx area

    const size_t SZ_ACT  = (size_t)NROWS * CDIM * 2;
    const size_t SZ_WBIG = (size_t)HDIM * CDIM * 2;
    const size_t SZ_R    = (size_t)NROWS * CDIM * 4;
    const size_t NEEDED  = 5 * SZ_ACT + SZ_R + SZ_WBIG;
    if (ws_size < NEEDED) return;

    char* ws = (char*)d_ws;
    u16* qb    = (u16*)(ws);
    u16* kb    = (u16*)(ws + 1 * SZ_ACT);
    u16* vb    = (u16*)(ws + 2 * SZ_ACT);
    u16* ctxb  = (u16*)(ws + 3 * SZ_ACT);
    u16* hb    = qb;
    u16* lnbuf = (u16*)(ws + 4 * SZ_ACT);
    u16* attB  = lnbuf;
    float* R   = (float*)(ws + 5 * SZ_ACT);
    u16* Wq    = (u16*)(ws + 5 * SZ_ACT + SZ_R);
    u16* Wk    = Wq + (size_t)CDIM * CDIM;
    u16* Wv    = Wk + (size_t)CDIM * CDIM;
    // (m,l) pairs overlay the weight pool: dead during each attention phase
    float2* ml = (float2*)Wq;

    const dim3 tb(256);
    GemmArgs ga;

    cvt_copy<<<dim3(3072), tb, 0, stream>>>(ctx, ctxb, NROWS * CDIM / 4);

    // ---- self-attention
    ln_kernel<<<dim3(NROWS), tb, 0, stream>>>(x, ln1g, ln1b, lnbuf);
    wtrans<<<dim3(24, 24), tb, 0, stream>>>(sa_wq, Wq, 768, 768);
    wtrans<<<dim3(24, 24), tb, 0, stream>>>(sa_wk, Wk, 768, 768);
    wtrans<<<dim3(24, 24), tb, 0, stream>>>(sa_wv, Wv, 768, 768);
    ga = GemmArgs{};
    ga.A[0] = lnbuf; ga.BT[0] = Wq; ga.bias[0] = sa_bq; ga.out[0] = qb; ga.alpha[0] = QSCALE;
    ga.A[1] = lnbuf; ga.BT[1] = Wk; ga.bias[1] = sa_bk; ga.out[1] = kb; ga.alpha[1] = 1.f;
    ga.A[2] = lnbuf; ga.BT[2] = Wv; ga.bias[2] = sa_bv; ga.out[2] = vb; ga.alpha[2] = 1.f;
    ga.M = 4096; ga.N = 768; ga.K = 768;
    gemm_bt<0, 128><<<dim3(32, 6, 3), tb, 0, stream>>>(ga);
    attn_split<<<dim3(32, 24, KVSPLIT), tb, 0, stream>>>(qb, kb, vb, Opart, ml);
    attn_merge<<<dim3(NROWS * CDIM / 1024), tb, 0, stream>>>(
        Opart, Opart + (size_t)NROWS * CDIM, ml, attB);
    wtrans<<<dim3(24, 24), tb, 0, stream>>>(sa_wo, Wq, 768, 768);
    ga = GemmArgs{};
    ga.A[0] = attB; ga.BT[0] = Wq; ga.bias[0] = sa_bo; ga.res[0] = x; ga.out[0] = R; ga.alpha[0] = 1.f;
    ga.M = 4096; ga.N = 768; ga.K = 768;
    gemm_bt<1, 64><<<dim3(64, 6, 1), tb, 0, stream>>>(ga);

    // ---- cross-attention
    ln_kernel<<<dim3(NROWS), tb, 0, stream>>>(R, ln2g, ln2b, lnbuf);
    wtrans<<<dim3(24, 24), tb, 0, stream>>>(xa_wq, Wq, 768, 768);
    wtrans<<<dim3(24, 24), tb, 0, stream>>>(xa_wk, Wk, 768, 768);
    wtrans<<<dim3(24, 24), tb, 0, stream>>>(xa_wv, Wv, 768, 768);
    ga = GemmArgs{};
    ga.A[0] = lnbuf; ga.BT[0] = Wq; ga.bias[0] = xa_bq; ga.out[0] = qb; ga.alpha[0] = QSCALE;
    ga.A[1] = ctxb;  ga.BT[1] = Wk; ga.bias[1] = xa_bk; ga.out[1] = kb; ga.alpha[1] = 1.f;
    ga.A[2] = ctxb;  ga.BT[2] = Wv; ga.bias[2] = xa_bv; ga.out[2] = vb; ga.alpha[2] = 1.f;
    ga.M = 4096; ga.N = 768; ga.K = 768;
    gemm_bt<0, 128><<<dim3(32, 6, 3), tb, 0, stream>>>(ga);
    attn_split<<<dim3(32, 24, KVSPLIT), tb, 0, stream>>>(qb, kb, vb, Opart, ml);
    attn_merge<<<dim3(NROWS * CDIM / 1024), tb, 0, stream>>>(
        Opart, Opart + (size_t)NROWS * CDIM, ml, attB);
    // context passthrough now that out_ctx's scratch role is over
    hipMemcpyAsync(out_ctx, ctx, (size_t)NROWS * CDIM * 4,
                   hipMemcpyDeviceToDevice, stream);
    wtrans<<<dim3(24, 24), tb, 0, stream>>>(xa_wo, Wq, 768, 768);
    ga = GemmArgs{};
    ga.A[0] = attB; ga.BT[0] = Wq; ga.bias[0] = xa_bo; ga.res[0] = R; ga.out[0] = R; ga.alpha[0] = 1.f;
    ga.M = 4096; ga.N = 768; ga.K = 768;
    gemm_bt<1, 64><<<dim3(64, 6, 1), tb, 0, stream>>>(ga);

    // ---- MLP
    ln_kernel<<<dim3(NROWS), tb, 0, stream>>>(R, ln3g, ln3b, lnbuf);
    wtrans<<<dim3(96, 24), tb, 0, stream>>>(m_w1, Wq, 768, 3072);
    ga = GemmArgs{};
    ga.A[0] = lnbuf; ga.BT[0] = Wq; ga.bias[0] = m_b1; ga.out[0] = hb; ga.alpha[0] = 1.f;
    ga.M = 4096; ga.N = 3072; ga.K = 768;
    gemm_bt<2, 128><<<dim3(32, 24, 1), tb, 0, stream>>>(ga);
    wtrans<<<dim3(24, 96), tb, 0, stream>>>(m_w2, Wq, 3072, 768);
    ga = GemmArgs{};
    ga.A[0] = hb; ga.BT[0] = Wq; ga.bias[0] = m_b2; ga.res[0] = R; ga.out[0] = out_x; ga.alpha[0] = 1.f;
    ga.M = 4096; ga.N = 768; ga.K = 3072;
    gemm_bt<1, 64><<<dim3(64, 6, 1), tb, 0, stream>>>(ga);

    (void)in_sizes; (void)n_in; (void)out_size;
}

// Round 12
// 362.359 us; speedup vs baseline: 1.4524x; 1.0830x over previous
//
#include <hip/hip_runtime.h>
#include <hip/hip_bf16.h>
#include <math.h>

#define CDIM 768
#define HDIM 3072
#define NROWS 4096   // B*T
#define TSEQ 2048
#define NHEAD 12
#define KVSPLIT 4
#define KVLEN (TSEQ / KVSPLIT)   // 512 rows per part

typedef unsigned short u16;
typedef unsigned int   u32;
typedef __attribute__((ext_vector_type(8))) short short8;
typedef __attribute__((ext_vector_type(4))) float f32x4;

// 1/sqrt(64) * log2(e): folds the softmax ln->log2 conversion into Q
#define QSCALE 0.18033688011112042f

static __device__ __forceinline__ u16 f2bf(float f) {
    u32 x = __float_as_uint(f);
    x += 0x7fffu + ((x >> 16) & 1u);
    return (u16)(x >> 16);
}
static __device__ __forceinline__ float bf2f(u16 x) {
    return __uint_as_float((u32)x << 16);
}
static __device__ __forceinline__ u32 cvt_pk_bf16(float lo, float hi) {
    u32 r;
    asm("v_cvt_pk_bf16_f32 %0, %1, %2" : "=v"(r) : "v"(lo), "v"(hi));
    return r;
}

#define GLL16(g, l)                                                            \
    __builtin_amdgcn_global_load_lds(                                          \
        (const __attribute__((address_space(1))) void*)(g),                    \
        (__attribute__((address_space(3))) void*)(l), 16, 0, 0)

// ---------------------------------------------------------------- transpose
__launch_bounds__(256)
__global__ void wtrans(const float* __restrict__ w, u16* __restrict__ wt,
                       int K, int N) {
    __shared__ float t[32][33];
    const int n0 = blockIdx.x * 32, k0 = blockIdx.y * 32;
    const int tx = threadIdx.x & 31, ty = threadIdx.x >> 5;
#pragma unroll
    for (int i = ty; i < 32; i += 8)
        t[i][tx] = w[(size_t)(k0 + i) * N + n0 + tx];
    __syncthreads();
#pragma unroll
    for (int i = ty; i < 32; i += 8)
        wt[(size_t)(n0 + i) * K + k0 + tx] = f2bf(t[tx][i]);
}

// 3 weights (768x768 each) in one dispatch via blockIdx.z
struct WT3 { const float* w[3]; u16* wt[3]; };
__launch_bounds__(256)
__global__ void wtrans3(WT3 a) {
    __shared__ float t[32][33];
    const float* __restrict__ w = a.w[blockIdx.z];
    u16* __restrict__ wt = a.wt[blockIdx.z];
    const int n0 = blockIdx.x * 32, k0 = blockIdx.y * 32;
    const int tx = threadIdx.x & 31, ty = threadIdx.x >> 5;
#pragma unroll
    for (int i = ty; i < 32; i += 8)
        t[i][tx] = w[(size_t)(k0 + i) * CDIM + n0 + tx];
    __syncthreads();
#pragma unroll
    for (int i = ty; i < 32; i += 8)
        wt[(size_t)(n0 + i) * CDIM + k0 + tx] = f2bf(t[tx][i]);
}

// ---------------------------------------------------------------- fp32 -> bf16 copy
__launch_bounds__(256)
__global__ void cvt_copy(const float* __restrict__ in, u16* __restrict__ out,
                         int n4) {
    int i = blockIdx.x * 256 + threadIdx.x;
    if (i >= n4) return;
    float4 v = ((const float4*)in)[i];
    ushort4 o;
    o.x = f2bf(v.x); o.y = f2bf(v.y); o.z = f2bf(v.z); o.w = f2bf(v.w);
    ((ushort4*)out)[i] = o;
}

// ---------------------------------------------------------------- layernorm
__launch_bounds__(256)
__global__ void ln_kernel(const float* __restrict__ x, const float* __restrict__ g,
                          const float* __restrict__ bta, u16* __restrict__ out) {
    const int row = blockIdx.x, tid = threadIdx.x;
    const float* xr = x + (size_t)row * CDIM;
    float v0 = xr[tid], v1 = xr[tid + 256], v2 = xr[tid + 512];
    __shared__ float red[8];
    float s = v0 + v1 + v2;
#pragma unroll
    for (int m = 1; m < 64; m <<= 1) s += __shfl_xor(s, m);
    if ((tid & 63) == 0) red[tid >> 6] = s;
    __syncthreads();
    const float mu = (red[0] + red[1] + red[2] + red[3]) * (1.f / CDIM);
    const float d0 = v0 - mu, d1 = v1 - mu, d2 = v2 - mu;
    float q = d0 * d0 + d1 * d1 + d2 * d2;
#pragma unroll
    for (int m = 1; m < 64; m <<= 1) q += __shfl_xor(q, m);
    if ((tid & 63) == 0) red[4 + (tid >> 6)] = q;
    __syncthreads();
    const float var = (red[4] + red[5] + red[6] + red[7]) * (1.f / CDIM);
    const float rstd = rsqrtf(var + 1e-5f);
    u16* orow = out + (size_t)row * CDIM;
    orow[tid]       = f2bf(d0 * rstd * g[tid]       + bta[tid]);
    orow[tid + 256] = f2bf(d1 * rstd * g[tid + 256] + bta[tid + 256]);
    orow[tid + 512] = f2bf(d2 * rstd * g[tid + 512] + bta[tid + 512]);
}

// ---------------------------------------------------------------- GEMM
// C[M,N] = A[M,K](bf16) * BT[N,K]^T(bf16) + bias.  BM x BN tile, BK=32,
// 4 waves (2x2), global_load_lds staging.  BN=64 variant gives 768-block
// grids for the lone GEMMs (>=3 blocks/CU hides the barrier drain, m114).
struct GemmArgs {
    const u16* A[3];
    const u16* BT[3];
    const float* bias[3];
    const float* res[3];
    void* out[3];
    float alpha[3];
    int M, N, K;
};

// EPI: 0 = (s+bias)*alpha -> bf16 ; 1 = res + s + bias -> f32 ; 2 = gelu -> bf16
template <int EPI, int BM, int BN = 128>
__launch_bounds__(256)
__global__ void gemm_bt(GemmArgs ga) {
    constexpr int MF = BM / 32, NF = BN / 32;
    __shared__ u16 Abuf[BM * 32];
    __shared__ u16 Bbuf[BN * 32];
    const int z = blockIdx.z;
    const u16* __restrict__ A  = ga.A[z];
    const u16* __restrict__ BT = ga.BT[z];
    const float* __restrict__ bias = ga.bias[z];
    const float* __restrict__ res  = ga.res[z];
    void* outv = ga.out[z];
    const float alpha = ga.alpha[z];
    const int N = ga.N, K = ga.K;

    const int tid = threadIdx.x;
    const int lane = tid & 63, w = tid >> 6;
    const int m0 = blockIdx.x * BM, n0 = blockIdx.y * BN;
    const int wr = (w >> 1) * (BM / 2), wc = (w & 1) * (BN / 2);
    const int lr = lane & 15, lc = lane >> 4;

    const int srowA = (BM == 128) ? (w * 32 + (lane >> 2)) : (tid >> 2);
    const int srowB = (BN == 128) ? (w * 32 + (lane >> 2)) : (tid >> 2);
    const int scol = (lane & 3) * 8;
    const u16* Ag = A + (size_t)(m0 + srowA) * K + scol;
    const u16* Bg = BT + (size_t)(n0 + srowB) * K + scol;
    char* Ab = (char*)Abuf + w * (BM == 128 ? 2048 : 1024);
    char* Bb = (char*)Bbuf + w * (BN == 128 ? 2048 : 1024);

    f32x4 acc[MF][NF];
#pragma unroll
    for (int m = 0; m < MF; ++m)
#pragma unroll
        for (int n = 0; n < NF; ++n) acc[m][n] = (f32x4){0.f, 0.f, 0.f, 0.f};

    const int nk = K >> 5;
    for (int kt = 0; kt < nk; ++kt) {
        const int ko = kt * 32;
        GLL16(Ag + ko, Ab);
        if constexpr (BM == 128) GLL16(Ag + 16 * K + ko, Ab + 1024);
        GLL16(Bg + ko, Bb);
        if constexpr (BN == 128) GLL16(Bg + 16 * K + ko, Bb + 1024);
        __syncthreads();
        short8 af[MF], bfv[NF];
#pragma unroll
        for (int m = 0; m < MF; ++m)
            af[m] = *(const short8*)((const char*)Abuf +
                                     (size_t)(wr + m * 16 + lr) * 64 + lc * 16);
#pragma unroll
        for (int n = 0; n < NF; ++n)
            bfv[n] = *(const short8*)((const char*)Bbuf +
                                      (size_t)(wc + n * 16 + lr) * 64 + lc * 16);
#pragma unroll
        for (int m = 0; m < MF; ++m)
#pragma unroll
            for (int n = 0; n < NF; ++n)
                acc[m][n] = __builtin_amdgcn_mfma_f32_16x16x32_bf16(
                    af[m], bfv[n], acc[m][n], 0, 0, 0);
        __syncthreads();
    }

#pragma unroll
    for (int n = 0; n < NF; ++n) {
        const int gc = n0 + wc + n * 16 + lr;
        const float bs = bias[gc];
#pragma unroll
        for (int m = 0; m < MF; ++m) {
            const int gr = m0 + wr + m * 16 + lc * 4;
#pragma unroll
            for (int r = 0; r < 4; ++r) {
                float v = (acc[m][n][r] + bs) * alpha;
                const size_t idx = (size_t)(gr + r) * N + gc;
                if constexpr (EPI == 0) {
                    ((u16*)outv)[idx] = f2bf(v);
                } else if constexpr (EPI == 1) {
                    ((float*)outv)[idx] = res[idx] + v;
                } else {
                    float gel = 0.5f * v * (1.0f + erff(v * 0.70710678118654752f));
                    ((u16*)outv)[idx] = f2bf(gel);
                }
            }
        }
    }
}

// ---------------------------------------------------------------- attention (split-KV)
// Swapped-operand flash attention (verified R10 inner loop) + KVSPLIT=4 +
// defer-max (skip rescale when the running max doesn't grow; P stays <= 1)
// + UNNORMALIZED bf16 partials written to d_out scratch.
__launch_bounds__(256)
__global__ void attn_split(const u16* __restrict__ Qb, const u16* __restrict__ Kb,
                           const u16* __restrict__ Vb, u16* __restrict__ Opart,
                           float2* __restrict__ ml) {
    __shared__ u16 Klds[64 * 72];
    __shared__ u16 Vt[64 * 72];
    const int tid = threadIdx.x;
    const int lane = tid & 63, w = tid >> 6;
    const int lr = lane & 15, lc = lane >> 4;
    const int b = blockIdx.y / NHEAD, h = blockIdx.y % NHEAD;
    const int z = blockIdx.z;
    const size_t qrow0 = (size_t)b * TSEQ + blockIdx.x * 64 + w * 16;
    const size_t krow0 = (size_t)b * TSEQ + (size_t)z * KVLEN;
    const int hc = h * 64;

    short8 qf0, qf1;
    {
        const u16* qp = Qb + (qrow0 + lr) * CDIM + hc + lc * 8;
        qf0 = *(const short8*)qp;
        qf1 = *(const short8*)(qp + 32);
    }
    f32x4 oacc[4];
#pragma unroll
    for (int r = 0; r < 4; ++r) oacc[r] = (f32x4){0.f, 0.f, 0.f, 0.f};
    float mrow = -3e38f, lrow = 0.f;

    const int stg_r = tid >> 2, stg_s = tid & 3;
    const u16* kg = Kb + (krow0 + stg_r) * CDIM + hc + stg_s * 16;
    const u16* vg = Vb + (krow0 + stg_r) * CDIM + hc + stg_s * 16;
    uint4 ka0 = *(const uint4*)kg, ka1 = *(const uint4*)(kg + 8);
    uint4 va0 = *(const uint4*)vg, va1 = *(const uint4*)(vg + 8);
    const int sig = ((stg_r >> 5) << 5) + (((stg_r >> 2) & 3) << 3) +
                    (((stg_r >> 4) & 1) << 2) + (stg_r & 3);
    char* vdst = (char*)Vt + ((2 * sig) ^ (stg_s << 5)) +
                 (size_t)(stg_s * 16) * 144;

    for (int kt = 0; kt < KVLEN / 64; ++kt) {
        __syncthreads();
        {
            *(uint4*)&Klds[stg_r * 72 + stg_s * 16]     = ka0;
            *(uint4*)&Klds[stg_r * 72 + stg_s * 16 + 8] = ka1;
            u16 tmp[16];
            *(uint4*)(tmp)     = va0;
            *(uint4*)(tmp + 8) = va1;
#pragma unroll
            for (int j = 0; j < 16; ++j)
                *(u16*)(vdst + (size_t)j * 144) = tmp[j];
        }
        if (kt < KVLEN / 64 - 1) {
            kg += 64 * CDIM; vg += 64 * CDIM;
            ka0 = *(const uint4*)kg; ka1 = *(const uint4*)(kg + 8);
            va0 = *(const uint4*)vg; va1 = *(const uint4*)(vg + 8);
        }
        __syncthreads();

        // S^T = K * Q^T : sf[fn][r] = S[q=lr][k = 16*fn + 4*lc + r]
        f32x4 sf[4];
#pragma unroll
        for (int fn = 0; fn < 4; ++fn) {
            const u16* kr = &Klds[(lr + fn * 16) * 72 + lc * 8];
            short8 kb0 = *(const short8*)kr;
            short8 kb1 = *(const short8*)(kr + 32);
            f32x4 t = (f32x4){0.f, 0.f, 0.f, 0.f};
            t = __builtin_amdgcn_mfma_f32_16x16x32_bf16(kb0, qf0, t, 0, 0, 0);
            t = __builtin_amdgcn_mfma_f32_16x16x32_bf16(kb1, qf1, t, 0, 0, 0);
            sf[fn] = t;
        }

        // tile max (per-lane q-row; reduce across the 4 lanes of the q-group)
        float pm;
        {
            float a0 = fmaxf(fmaxf(sf[0][0], sf[0][1]), fmaxf(sf[0][2], sf[0][3]));
            float a1 = fmaxf(fmaxf(sf[1][0], sf[1][1]), fmaxf(sf[1][2], sf[1][3]));
            float a2 = fmaxf(fmaxf(sf[2][0], sf[2][1]), fmaxf(sf[2][2], sf[2][3]));
            float a3 = fmaxf(fmaxf(sf[3][0], sf[3][1]), fmaxf(sf[3][2], sf[3][3]));
            pm = fmaxf(fmaxf(a0, a1), fmaxf(a2, a3));
            pm = fmaxf(pm, __shfl_xor(pm, 16));
            pm = fmaxf(pm, __shfl_xor(pm, 32));
        }
        // defer-max: only rescale when some q-row's max grew (wave-uniform)
        if (!__all(pm <= mrow)) {
            const float mn = fmaxf(mrow, pm);
            const float corr = exp2f(mrow - mn);
            mrow = mn;
            lrow *= corr;
#pragma unroll
            for (int fd = 0; fd < 4; ++fd)
#pragma unroll
                for (int r = 0; r < 4; ++r) oacc[fd][r] *= corr;
        }
        float rs;
        {
#pragma unroll
            for (int fn = 0; fn < 4; ++fn)
#pragma unroll
                for (int r = 0; r < 4; ++r) sf[fn][r] = exp2f(sf[fn][r] - mrow);
            float s0 = (sf[0][0] + sf[0][1]) + (sf[0][2] + sf[0][3]);
            float s1 = (sf[1][0] + sf[1][1]) + (sf[1][2] + sf[1][3]);
            float s2 = (sf[2][0] + sf[2][1]) + (sf[2][2] + sf[2][3]);
            float s3 = (sf[3][0] + sf[3][1]) + (sf[3][2] + sf[3][3]);
            rs = (s0 + s1) + (s2 + s3);
            rs += __shfl_xor(rs, 16);
            rs += __shfl_xor(rs, 32);
        }
        lrow += rs;

        int4 pw0, pw1;
        pw0.x = cvt_pk_bf16(sf[0][0], sf[0][1]);
        pw0.y = cvt_pk_bf16(sf[0][2], sf[0][3]);
        pw0.z = cvt_pk_bf16(sf[1][0], sf[1][1]);
        pw0.w = cvt_pk_bf16(sf[1][2], sf[1][3]);
        pw1.x = cvt_pk_bf16(sf[2][0], sf[2][1]);
        pw1.y = cvt_pk_bf16(sf[2][2], sf[2][3]);
        pw1.z = cvt_pk_bf16(sf[3][0], sf[3][1]);
        pw1.w = cvt_pk_bf16(sf[3][2], sf[3][3]);
        short8 pb0 = *(short8*)&pw0;
        short8 pb1 = *(short8*)&pw1;

#pragma unroll
        for (int fd = 0; fd < 4; ++fd) {
            const char* vtb = (const char*)Vt + (size_t)(lr + fd * 16) * 144;
            short8 vb0 = *(const short8*)(vtb + ((lc * 16) ^ (fd * 32)));
            short8 vb1 = *(const short8*)(vtb + ((lc * 16 + 64) ^ (fd * 32)));
            oacc[fd] = __builtin_amdgcn_mfma_f32_16x16x32_bf16(vb0, pb0, oacc[fd], 0, 0, 0);
            oacc[fd] = __builtin_amdgcn_mfma_f32_16x16x32_bf16(vb1, pb1, oacc[fd], 0, 0, 0);
        }
    }

    // epilogue: UNNORMALIZED bf16 partial + (m,l); lane holds O[q=lr][d=16fd+4lc+r]
    u16* obase = Opart + (size_t)z * NROWS * CDIM + (qrow0 + lr) * CDIM + hc + lc * 4;
#pragma unroll
    for (int fd = 0; fd < 4; ++fd) {
        ushort4 o;
        o.x = f2bf(oacc[fd][0]); o.y = f2bf(oacc[fd][1]);
        o.z = f2bf(oacc[fd][2]); o.w = f2bf(oacc[fd][3]);
        *(ushort4*)(obase + fd * 16) = o;
    }
    if (lc == 0)
        ml[((size_t)z * NROWS + qrow0 + lr) * NHEAD + h] = (float2){mrow, lrow};
}

// ---------------------------------------------------------------- merge (4 parts)
__launch_bounds__(256)
__global__ void attn_merge4(const u16* __restrict__ P, const float2* __restrict__ ml,
                            u16* __restrict__ out) {
    const int i4 = blockIdx.x * 256 + threadIdx.x;   // 4-elem chunk index
    const size_t base = (size_t)i4 * 4;
    const int row = (int)(base / CDIM);
    const int head = (int)(base - (size_t)row * CDIM) >> 6;
    float2 a[KVSPLIT];
    float M = -3e38f;
#pragma unroll
    for (int z = 0; z < KVSPLIT; ++z) {
        a[z] = ml[((size_t)z * NROWS + row) * NHEAD + head];
        M = fmaxf(M, a[z].x);
    }
    float den = 0.f, e[KVSPLIT];
#pragma unroll
    for (int z = 0; z < KVSPLIT; ++z) {
        e[z] = exp2f(a[z].x - M);
        den += a[z].y * e[z];
    }
    const float rden = 1.f / den;
    float o0 = 0.f, o1 = 0.f, o2 = 0.f, o3 = 0.f;
#pragma unroll
    for (int z = 0; z < KVSPLIT; ++z) {
        ushort4 p = *(const ushort4*)(P + (size_t)z * NROWS * CDIM + base);
        o0 += bf2f(p.x) * e[z];
        o1 += bf2f(p.y) * e[z];
        o2 += bf2f(p.z) * e[z];
        o3 += bf2f(p.w) * e[z];
    }
    ushort4 o;
    o.x = f2bf(o0 * rden); o.y = f2bf(o1 * rden);
    o.z = f2bf(o2 * rden); o.w = f2bf(o3 * rden);
    *(ushort4*)(out + base) = o;
}

// ---------------------------------------------------------------- launch
extern "C" void kernel_launch(void* const* d_in, const int* in_sizes, int n_in,
                              void* d_out, int out_size, void* d_ws, size_t ws_size,
                              hipStream_t stream) {
    const float* x     = (const float*)d_in[0];
    const float* ctx   = (const float*)d_in[1];
    const float* ln1g  = (const float*)d_in[2];
    const float* ln1b  = (const float*)d_in[3];
    const float* ln2g  = (const float*)d_in[4];
    const float* ln2b  = (const float*)d_in[5];
    const float* ln3g  = (const float*)d_in[6];
    const float* ln3b  = (const float*)d_in[7];
    const float* sa_wq = (const float*)d_in[8];
    const float* sa_bq = (const float*)d_in[9];
    const float* sa_wk = (const float*)d_in[10];
    const float* sa_bk = (const float*)d_in[11];
    const float* sa_wv = (const float*)d_in[12];
    const float* sa_bv = (const float*)d_in[13];
    const float* sa_wo = (const float*)d_in[14];
    const float* sa_bo = (const float*)d_in[15];
    const float* xa_wq = (const float*)d_in[16];
    const float* xa_bq = (const float*)d_in[17];
    const float* xa_wk = (const float*)d_in[18];
    const float* xa_bk = (const float*)d_in[19];
    const float* xa_wv = (const float*)d_in[20];
    const float* xa_bv = (const float*)d_in[21];
    const float* xa_wo = (const float*)d_in[22];
    const float* xa_bo = (const float*)d_in[23];
    const float* m_w1  = (const float*)d_in[24];
    const float* m_b1  = (const float*)d_in[25];
    const float* m_w2  = (const float*)d_in[26];
    const float* m_b2  = (const float*)d_in[27];

    float* out_x   = (float*)d_out;
    float* out_ctx = out_x + (size_t)NROWS * CDIM;
    // d_out doubles as bf16 split-KV partial scratch (4 x NROWS*CDIM u16 =
    // exactly out_size bytes) until the final out_ctx memcpy / out_x GEMM.
    u16* Opart = (u16*)d_out;

    const size_t SZ_ACT  = (size_t)NROWS * CDIM * 2;
    const size_t SZ_WBIG = (size_t)HDIM * CDIM * 2;
    const size_t SZ_R    = (size_t)NROWS * CDIM * 4;
    const size_t NEEDED  = 5 * SZ_ACT + SZ_R + SZ_WBIG;
    if (ws_size < NEEDED) return;

    char* ws = (char*)d_ws;
    u16* qb    = (u16*)(ws);
    u16* kb    = (u16*)(ws + 1 * SZ_ACT);
    u16* vb    = (u16*)(ws + 2 * SZ_ACT);
    u16* ctxb  = (u16*)(ws + 3 * SZ_ACT);
    u16* hb    = qb;
    u16* lnbuf = (u16*)(ws + 4 * SZ_ACT);
    u16* attB  = lnbuf;
    float* R   = (float*)(ws + 5 * SZ_ACT);
    u16* Wq    = (u16*)(ws + 5 * SZ_ACT + SZ_R);
    u16* Wk    = Wq + (size_t)CDIM * CDIM;
    u16* Wv    = Wk + (size_t)CDIM * CDIM;
    // (m,l) pairs overlay the weight pool: dead during each attention phase
    float2* ml = (float2*)Wq;

    const dim3 tb(256);
    GemmArgs ga;
    WT3 wg;

    cvt_copy<<<dim3(3072), tb, 0, stream>>>(ctx, ctxb, NROWS * CDIM / 4);

    // ---- self-attention
    ln_kernel<<<dim3(NROWS), tb, 0, stream>>>(x, ln1g, ln1b, lnbuf);
    wg.w[0] = sa_wq; wg.w[1] = sa_wk; wg.w[2] = sa_wv;
    wg.wt[0] = Wq;   wg.wt[1] = Wk;   wg.wt[2] = Wv;
    wtrans3<<<dim3(24, 24, 3), tb, 0, stream>>>(wg);
    ga = GemmArgs{};
    ga.A[0] = lnbuf; ga.BT[0] = Wq; ga.bias[0] = sa_bq; ga.out[0] = qb; ga.alpha[0] = QSCALE;
    ga.A[1] = lnbuf; ga.BT[1] = Wk; ga.bias[1] = sa_bk; ga.out[1] = kb; ga.alpha[1] = 1.f;
    ga.A[2] = lnbuf; ga.BT[2] = Wv; ga.bias[2] = sa_bv; ga.out[2] = vb; ga.alpha[2] = 1.f;
    ga.M = 4096; ga.N = 768; ga.K = 768;
    gemm_bt<0, 128><<<dim3(32, 6, 3), tb, 0, stream>>>(ga);
    attn_split<<<dim3(32, 24, KVSPLIT), tb, 0, stream>>>(qb, kb, vb, Opart, ml);
    attn_merge4<<<dim3(NROWS * CDIM / 1024), tb, 0, stream>>>(Opart, ml, attB);
    wtrans<<<dim3(24, 24), tb, 0, stream>>>(sa_wo, Wq, 768, 768);
    ga = GemmArgs{};
    ga.A[0] = attB; ga.BT[0] = Wq; ga.bias[0] = sa_bo; ga.res[0] = x; ga.out[0] = R; ga.alpha[0] = 1.f;
    ga.M = 4096; ga.N = 768; ga.K = 768;
    gemm_bt<1, 64, 64><<<dim3(64, 12, 1), tb, 0, stream>>>(ga);

    // ---- cross-attention
    ln_kernel<<<dim3(NROWS), tb, 0, stream>>>(R, ln2g, ln2b, lnbuf);
    wg.w[0] = xa_wq; wg.w[1] = xa_wk; wg.w[2] = xa_wv;
    wg.wt[0] = Wq;   wg.wt[1] = Wk;   wg.wt[2] = Wv;
    wtrans3<<<dim3(24, 24, 3), tb, 0, stream>>>(wg);
    ga = GemmArgs{};
    ga.A[0] = lnbuf; ga.BT[0] = Wq; ga.bias[0] = xa_bq; ga.out[0] = qb; ga.alpha[0] = QSCALE;
    ga.A[1] = ctxb;  ga.BT[1] = Wk; ga.bias[1] = xa_bk; ga.out[1] = kb; ga.alpha[1] = 1.f;
    ga.A[2] = ctxb;  ga.BT[2] = Wv; ga.bias[2] = xa_bv; ga.out[2] = vb; ga.alpha[2] = 1.f;
    ga.M = 4096; ga.N = 768; ga.K = 768;
    gemm_bt<0, 128><<<dim3(32, 6, 3), tb, 0, stream>>>(ga);
    attn_split<<<dim3(32, 24, KVSPLIT), tb, 0, stream>>>(qb, kb, vb, Opart, ml);
    attn_merge4<<<dim3(NROWS * CDIM / 1024), tb, 0, stream>>>(Opart, ml, attB);
    // context passthrough now that d_out's scratch role is over
    hipMemcpyAsync(out_ctx, ctx, (size_t)NROWS * CDIM * 4,
                   hipMemcpyDeviceToDevice, stream);
    wtrans<<<dim3(24, 24), tb, 0, stream>>>(xa_wo, Wq, 768, 768);
    ga = GemmArgs{};
    ga.A[0] = attB; ga.BT[0] = Wq; ga.bias[0] = xa_bo; ga.res[0] = R; ga.out[0] = R; ga.alpha[0] = 1.f;
    ga.M = 4096; ga.N = 768; ga.K = 768;
    gemm_bt<1, 64, 64><<<dim3(64, 12, 1), tb, 0, stream>>>(ga);

    // ---- MLP
    ln_kernel<<<dim3(NROWS), tb, 0, stream>>>(R, ln3g, ln3b, lnbuf);
    wtrans<<<dim3(96, 24), tb, 0, stream>>>(m_w1, Wq, 768, 3072);
    ga = GemmArgs{};
    ga.A[0] = lnbuf; ga.BT[0] = Wq; ga.bias[0] = m_b1; ga.out[0] = hb; ga.alpha[0] = 1.f;
    ga.M = 4096; ga.N = 3072; ga.K = 768;
    gemm_bt<2, 128><<<dim3(32, 24, 1), tb, 0, stream>>>(ga);
    wtrans<<<dim3(24, 96), tb, 0, stream>>>(m_w2, Wq, 3072, 768);
    ga = GemmArgs{};
    ga.A[0] = hb; ga.BT[0] = Wq; ga.bias[0] = m_b2; ga.res[0] = R; ga.out[0] = out_x; ga.alpha[0] = 1.f;
    ga.M = 4096; ga.N = 768; ga.K = 3072;
    gemm_bt<1, 64, 64><<<dim3(64, 12, 1), tb, 0, stream>>>(ga);

    (void)in_sizes; (void)n_in; (void)out_size;
}

// Round 13
// 340.718 us; speedup vs baseline: 1.5447x; 1.0635x over previous
//
#include <hip/hip_runtime.h>
#include <hip/hip_bf16.h>
#include <math.h>

#define CDIM 768
#define HDIM 3072
#define NROWS 4096   // B*T
#define TSEQ 2048
#define NHEAD 12
#define KVSPLIT 4
#define KVLEN (TSEQ / KVSPLIT)   // 512 rows per part

typedef unsigned short u16;
typedef unsigned int   u32;
typedef __attribute__((ext_vector_type(8))) short short8;
typedef __attribute__((ext_vector_type(4))) float f32x4;

// 1/sqrt(64) * log2(e): folds the softmax ln->log2 conversion into Q
#define QSCALE 0.18033688011112042f

static __device__ __forceinline__ u16 f2bf(float f) {
    u32 x = __float_as_uint(f);
    x += 0x7fffu + ((x >> 16) & 1u);
    return (u16)(x >> 16);
}
static __device__ __forceinline__ float bf2f(u16 x) {
    return __uint_as_float((u32)x << 16);
}
static __device__ __forceinline__ u32 cvt_pk_bf16(float lo, float hi) {
    u32 r;
    asm("v_cvt_pk_bf16_f32 %0, %1, %2" : "=v"(r) : "v"(lo), "v"(hi));
    return r;
}

#define GLL16(g, l)                                                            \
    __builtin_amdgcn_global_load_lds(                                          \
        (const __attribute__((address_space(1))) void*)(g),                    \
        (__attribute__((address_space(3))) void*)(l), 16, 0, 0)

// ---------------------------------------------------------------- transpose
__launch_bounds__(256)
__global__ void wtrans(const float* __restrict__ w, u16* __restrict__ wt,
                       int K, int N) {
    __shared__ float t[32][33];
    const int n0 = blockIdx.x * 32, k0 = blockIdx.y * 32;
    const int tx = threadIdx.x & 31, ty = threadIdx.x >> 5;
#pragma unroll
    for (int i = ty; i < 32; i += 8)
        t[i][tx] = w[(size_t)(k0 + i) * N + n0 + tx];
    __syncthreads();
#pragma unroll
    for (int i = ty; i < 32; i += 8)
        wt[(size_t)(n0 + i) * K + k0 + tx] = f2bf(t[tx][i]);
}

// 4 weights (768x768 each) in one dispatch via blockIdx.z
struct WT4 { const float* w[4]; u16* wt[4]; };
__launch_bounds__(256)
__global__ void wtrans4(WT4 a) {
    __shared__ float t[32][33];
    const float* __restrict__ w = a.w[blockIdx.z];
    u16* __restrict__ wt = a.wt[blockIdx.z];
    const int n0 = blockIdx.x * 32, k0 = blockIdx.y * 32;
    const int tx = threadIdx.x & 31, ty = threadIdx.x >> 5;
#pragma unroll
    for (int i = ty; i < 32; i += 8)
        t[i][tx] = w[(size_t)(k0 + i) * CDIM + n0 + tx];
    __syncthreads();
#pragma unroll
    for (int i = ty; i < 32; i += 8)
        wt[(size_t)(n0 + i) * CDIM + k0 + tx] = f2bf(t[tx][i]);
}

// ---------------------------------------------------------------- fp32 -> bf16 copy
__launch_bounds__(256)
__global__ void cvt_copy(const float* __restrict__ in, u16* __restrict__ out,
                         int n4) {
    int i = blockIdx.x * 256 + threadIdx.x;
    if (i >= n4) return;
    float4 v = ((const float4*)in)[i];
    ushort4 o;
    o.x = f2bf(v.x); o.y = f2bf(v.y); o.z = f2bf(v.z); o.w = f2bf(v.w);
    ((ushort4*)out)[i] = o;
}

// ---------------------------------------------------------------- layernorm
__launch_bounds__(256)
__global__ void ln_kernel(const float* __restrict__ x, const float* __restrict__ g,
                          const float* __restrict__ bta, u16* __restrict__ out) {
    const int row = blockIdx.x, tid = threadIdx.x;
    const float* xr = x + (size_t)row * CDIM;
    float v0 = xr[tid], v1 = xr[tid + 256], v2 = xr[tid + 512];
    __shared__ float red[8];
    float s = v0 + v1 + v2;
#pragma unroll
    for (int m = 1; m < 64; m <<= 1) s += __shfl_xor(s, m);
    if ((tid & 63) == 0) red[tid >> 6] = s;
    __syncthreads();
    const float mu = (red[0] + red[1] + red[2] + red[3]) * (1.f / CDIM);
    const float d0 = v0 - mu, d1 = v1 - mu, d2 = v2 - mu;
    float q = d0 * d0 + d1 * d1 + d2 * d2;
#pragma unroll
    for (int m = 1; m < 64; m <<= 1) q += __shfl_xor(q, m);
    if ((tid & 63) == 0) red[4 + (tid >> 6)] = q;
    __syncthreads();
    const float var = (red[4] + red[5] + red[6] + red[7]) * (1.f / CDIM);
    const float rstd = rsqrtf(var + 1e-5f);
    u16* orow = out + (size_t)row * CDIM;
    orow[tid]       = f2bf(d0 * rstd * g[tid]       + bta[tid]);
    orow[tid + 256] = f2bf(d1 * rstd * g[tid + 256] + bta[tid + 256]);
    orow[tid + 512] = f2bf(d2 * rstd * g[tid + 512] + bta[tid + 512]);
}

// ---------------------------------------------------------------- GEMM (unchanged from R12)
struct GemmArgs {
    const u16* A[3];
    const u16* BT[3];
    const float* bias[3];
    const float* res[3];
    void* out[3];
    float alpha[3];
    int M, N, K;
};

// EPI: 0 = (s+bias)*alpha -> bf16 ; 1 = res + s + bias -> f32 ; 2 = gelu -> bf16
template <int EPI, int BM, int BN = 128>
__launch_bounds__(256)
__global__ void gemm_bt(GemmArgs ga) {
    constexpr int MF = BM / 32, NF = BN / 32;
    __shared__ u16 Abuf[BM * 32];
    __shared__ u16 Bbuf[BN * 32];
    const int z = blockIdx.z;
    const u16* __restrict__ A  = ga.A[z];
    const u16* __restrict__ BT = ga.BT[z];
    const float* __restrict__ bias = ga.bias[z];
    const float* __restrict__ res  = ga.res[z];
    void* outv = ga.out[z];
    const float alpha = ga.alpha[z];
    const int N = ga.N, K = ga.K;

    const int tid = threadIdx.x;
    const int lane = tid & 63, w = tid >> 6;
    const int m0 = blockIdx.x * BM, n0 = blockIdx.y * BN;
    const int wr = (w >> 1) * (BM / 2), wc = (w & 1) * (BN / 2);
    const int lr = lane & 15, lc = lane >> 4;

    const int srowA = (BM == 128) ? (w * 32 + (lane >> 2)) : (tid >> 2);
    const int srowB = (BN == 128) ? (w * 32 + (lane >> 2)) : (tid >> 2);
    const int scol = (lane & 3) * 8;
    const u16* Ag = A + (size_t)(m0 + srowA) * K + scol;
    const u16* Bg = BT + (size_t)(n0 + srowB) * K + scol;
    char* Ab = (char*)Abuf + w * (BM == 128 ? 2048 : 1024);
    char* Bb = (char*)Bbuf + w * (BN == 128 ? 2048 : 1024);

    f32x4 acc[MF][NF];
#pragma unroll
    for (int m = 0; m < MF; ++m)
#pragma unroll
        for (int n = 0; n < NF; ++n) acc[m][n] = (f32x4){0.f, 0.f, 0.f, 0.f};

    const int nk = K >> 5;
    for (int kt = 0; kt < nk; ++kt) {
        const int ko = kt * 32;
        GLL16(Ag + ko, Ab);
        if constexpr (BM == 128) GLL16(Ag + 16 * K + ko, Ab + 1024);
        GLL16(Bg + ko, Bb);
        if constexpr (BN == 128) GLL16(Bg + 16 * K + ko, Bb + 1024);
        __syncthreads();
        short8 af[MF], bfv[NF];
#pragma unroll
        for (int m = 0; m < MF; ++m)
            af[m] = *(const short8*)((const char*)Abuf +
                                     (size_t)(wr + m * 16 + lr) * 64 + lc * 16);
#pragma unroll
        for (int n = 0; n < NF; ++n)
            bfv[n] = *(const short8*)((const char*)Bbuf +
                                      (size_t)(wc + n * 16 + lr) * 64 + lc * 16);
#pragma unroll
        for (int m = 0; m < MF; ++m)
#pragma unroll
            for (int n = 0; n < NF; ++n)
                acc[m][n] = __builtin_amdgcn_mfma_f32_16x16x32_bf16(
                    af[m], bfv[n], acc[m][n], 0, 0, 0);
        __syncthreads();
    }

#pragma unroll
    for (int n = 0; n < NF; ++n) {
        const int gc = n0 + wc + n * 16 + lr;
        const float bs = bias[gc];
#pragma unroll
        for (int m = 0; m < MF; ++m) {
            const int gr = m0 + wr + m * 16 + lc * 4;
#pragma unroll
            for (int r = 0; r < 4; ++r) {
                float v = (acc[m][n][r] + bs) * alpha;
                const size_t idx = (size_t)(gr + r) * N + gc;
                if constexpr (EPI == 0) {
                    ((u16*)outv)[idx] = f2bf(v);
                } else if constexpr (EPI == 1) {
                    ((float*)outv)[idx] = res[idx] + v;
                } else {
                    float gel = 0.5f * v * (1.0f + erff(v * 0.70710678118654752f));
                    ((u16*)outv)[idx] = f2bf(gel);
                }
            }
        }
    }
}

// ---------------------------------------------------------------- attention helpers
static __device__ __forceinline__ void softmax_pack(f32x4 sf[4], float& mrow,
                                                    float& lrow, f32x4 oacc[4],
                                                    short8& p0, short8& p1) {
    float pm;
    {
        float a0 = fmaxf(fmaxf(sf[0][0], sf[0][1]), fmaxf(sf[0][2], sf[0][3]));
        float a1 = fmaxf(fmaxf(sf[1][0], sf[1][1]), fmaxf(sf[1][2], sf[1][3]));
        float a2 = fmaxf(fmaxf(sf[2][0], sf[2][1]), fmaxf(sf[2][2], sf[2][3]));
        float a3 = fmaxf(fmaxf(sf[3][0], sf[3][1]), fmaxf(sf[3][2], sf[3][3]));
        pm = fmaxf(fmaxf(a0, a1), fmaxf(a2, a3));
        pm = fmaxf(pm, __shfl_xor(pm, 16));
        pm = fmaxf(pm, __shfl_xor(pm, 32));
    }
    // defer-max: only rescale when some q-row's max grew (wave-uniform)
    if (!__all(pm <= mrow)) {
        const float mn = fmaxf(mrow, pm);
        const float corr = exp2f(mrow - mn);
        mrow = mn;
        lrow *= corr;
#pragma unroll
        for (int fd = 0; fd < 4; ++fd)
#pragma unroll
            for (int r = 0; r < 4; ++r) oacc[fd][r] *= corr;
    }
#pragma unroll
    for (int fn = 0; fn < 4; ++fn)
#pragma unroll
        for (int r = 0; r < 4; ++r) sf[fn][r] = exp2f(sf[fn][r] - mrow);
    float rs;
    {
        float s0 = (sf[0][0] + sf[0][1]) + (sf[0][2] + sf[0][3]);
        float s1 = (sf[1][0] + sf[1][1]) + (sf[1][2] + sf[1][3]);
        float s2 = (sf[2][0] + sf[2][1]) + (sf[2][2] + sf[2][3]);
        float s3 = (sf[3][0] + sf[3][1]) + (sf[3][2] + sf[3][3]);
        rs = (s0 + s1) + (s2 + s3);
        rs += __shfl_xor(rs, 16);
        rs += __shfl_xor(rs, 32);
    }
    lrow += rs;
    int4 pw0, pw1;
    pw0.x = cvt_pk_bf16(sf[0][0], sf[0][1]);
    pw0.y = cvt_pk_bf16(sf[0][2], sf[0][3]);
    pw0.z = cvt_pk_bf16(sf[1][0], sf[1][1]);
    pw0.w = cvt_pk_bf16(sf[1][2], sf[1][3]);
    pw1.x = cvt_pk_bf16(sf[2][0], sf[2][1]);
    pw1.y = cvt_pk_bf16(sf[2][2], sf[2][3]);
    pw1.z = cvt_pk_bf16(sf[3][0], sf[3][1]);
    pw1.w = cvt_pk_bf16(sf[3][2], sf[3][3]);
    p0 = *(short8*)&pw0;
    p1 = *(short8*)&pw1;
}

// ---------------------------------------------------------------- attention (split-KV, 128q/block)
// Swapped-operand flash attention (R10-verified layouts). Each wave owns TWO
// 16-row q-groups (A: rows blockIdx.x*128 + w*16, B: +64); K/V staged once per
// tile and every LDS fragment read feeds both groups' MFMAs.
__launch_bounds__(256, 4)
__global__ void attn_split(const u16* __restrict__ Qb, const u16* __restrict__ Kb,
                           const u16* __restrict__ Vb, u16* __restrict__ Opart,
                           float2* __restrict__ ml) {
    __shared__ u16 Klds[64 * 72];
    __shared__ u16 Vt[64 * 72];
    const int tid = threadIdx.x;
    const int lane = tid & 63, w = tid >> 6;
    const int lr = lane & 15, lc = lane >> 4;
    const int b = blockIdx.y / NHEAD, h = blockIdx.y % NHEAD;
    const int z = blockIdx.z;
    const size_t qrowA = (size_t)b * TSEQ + blockIdx.x * 128 + w * 16;
    const size_t qrowB = qrowA + 64;
    const size_t krow0 = (size_t)b * TSEQ + (size_t)z * KVLEN;
    const int hc = h * 64;

    short8 qa0, qa1, qb0, qb1;
    {
        const u16* qp = Qb + (qrowA + lr) * CDIM + hc + lc * 8;
        qa0 = *(const short8*)qp;
        qa1 = *(const short8*)(qp + 32);
        const u16* qp2 = Qb + (qrowB + lr) * CDIM + hc + lc * 8;
        qb0 = *(const short8*)qp2;
        qb1 = *(const short8*)(qp2 + 32);
    }
    f32x4 oaccA[4], oaccB[4];
#pragma unroll
    for (int r = 0; r < 4; ++r) {
        oaccA[r] = (f32x4){0.f, 0.f, 0.f, 0.f};
        oaccB[r] = (f32x4){0.f, 0.f, 0.f, 0.f};
    }
    float mA = -3e38f, lA = 0.f, mB = -3e38f, lB = 0.f;

    const int stg_r = tid >> 2, stg_s = tid & 3;
    const u16* kg = Kb + (krow0 + stg_r) * CDIM + hc + stg_s * 16;
    const u16* vg = Vb + (krow0 + stg_r) * CDIM + hc + stg_s * 16;
    uint4 ka0 = *(const uint4*)kg, ka1 = *(const uint4*)(kg + 8);
    uint4 va0 = *(const uint4*)vg, va1 = *(const uint4*)(vg + 8);
    const int sig = ((stg_r >> 5) << 5) + (((stg_r >> 2) & 3) << 3) +
                    (((stg_r >> 4) & 1) << 2) + (stg_r & 3);
    char* vdst = (char*)Vt + ((2 * sig) ^ (stg_s << 5)) +
                 (size_t)(stg_s * 16) * 144;

    for (int kt = 0; kt < KVLEN / 64; ++kt) {
        __syncthreads();
        {
            *(uint4*)&Klds[stg_r * 72 + stg_s * 16]     = ka0;
            *(uint4*)&Klds[stg_r * 72 + stg_s * 16 + 8] = ka1;
            u16 tmp[16];
            *(uint4*)(tmp)     = va0;
            *(uint4*)(tmp + 8) = va1;
#pragma unroll
            for (int j = 0; j < 16; ++j)
                *(u16*)(vdst + (size_t)j * 144) = tmp[j];
        }
        if (kt < KVLEN / 64 - 1) {
            kg += 64 * CDIM; vg += 64 * CDIM;
            ka0 = *(const uint4*)kg; ka1 = *(const uint4*)(kg + 8);
            va0 = *(const uint4*)vg; va1 = *(const uint4*)(vg + 8);
        }
        __syncthreads();

        // S^T = K * Q^T for both q-groups; each K fragment read used twice
        f32x4 sfA[4], sfB[4];
#pragma unroll
        for (int fn = 0; fn < 4; ++fn) {
            const u16* kr = &Klds[(lr + fn * 16) * 72 + lc * 8];
            short8 kb0 = *(const short8*)kr;
            short8 kb1 = *(const short8*)(kr + 32);
            f32x4 t = (f32x4){0.f, 0.f, 0.f, 0.f};
            t = __builtin_amdgcn_mfma_f32_16x16x32_bf16(kb0, qa0, t, 0, 0, 0);
            t = __builtin_amdgcn_mfma_f32_16x16x32_bf16(kb1, qa1, t, 0, 0, 0);
            sfA[fn] = t;
            f32x4 u = (f32x4){0.f, 0.f, 0.f, 0.f};
            u = __builtin_amdgcn_mfma_f32_16x16x32_bf16(kb0, qb0, u, 0, 0, 0);
            u = __builtin_amdgcn_mfma_f32_16x16x32_bf16(kb1, qb1, u, 0, 0, 0);
            sfB[fn] = u;
        }

        short8 pA0, pA1, pB0, pB1;
        softmax_pack(sfA, mA, lA, oaccA, pA0, pA1);
        softmax_pack(sfB, mB, lB, oaccB, pB0, pB1);

        // O^T += V^T * P^T ; each V fragment read used twice
#pragma unroll
        for (int fd = 0; fd < 4; ++fd) {
            const char* vtb = (const char*)Vt + (size_t)(lr + fd * 16) * 144;
            short8 vb0 = *(const short8*)(vtb + ((lc * 16) ^ (fd * 32)));
            short8 vb1 = *(const short8*)(vtb + ((lc * 16 + 64) ^ (fd * 32)));
            oaccA[fd] = __builtin_amdgcn_mfma_f32_16x16x32_bf16(vb0, pA0, oaccA[fd], 0, 0, 0);
            oaccA[fd] = __builtin_amdgcn_mfma_f32_16x16x32_bf16(vb1, pA1, oaccA[fd], 0, 0, 0);
            oaccB[fd] = __builtin_amdgcn_mfma_f32_16x16x32_bf16(vb0, pB0, oaccB[fd], 0, 0, 0);
            oaccB[fd] = __builtin_amdgcn_mfma_f32_16x16x32_bf16(vb1, pB1, oaccB[fd], 0, 0, 0);
        }
    }

    // epilogue: UNNORMALIZED bf16 partials + (m,l) for both groups
    u16* oA = Opart + (size_t)z * NROWS * CDIM + (qrowA + lr) * CDIM + hc + lc * 4;
    u16* oB = Opart + (size_t)z * NROWS * CDIM + (qrowB + lr) * CDIM + hc + lc * 4;
#pragma unroll
    for (int fd = 0; fd < 4; ++fd) {
        ushort4 o;
        o.x = f2bf(oaccA[fd][0]); o.y = f2bf(oaccA[fd][1]);
        o.z = f2bf(oaccA[fd][2]); o.w = f2bf(oaccA[fd][3]);
        *(ushort4*)(oA + fd * 16) = o;
        o.x = f2bf(oaccB[fd][0]); o.y = f2bf(oaccB[fd][1]);
        o.z = f2bf(oaccB[fd][2]); o.w = f2bf(oaccB[fd][3]);
        *(ushort4*)(oB + fd * 16) = o;
    }
    if (lc == 0) {
        ml[((size_t)z * NROWS + qrowA + lr) * NHEAD + h] = (float2){mA, lA};
        ml[((size_t)z * NROWS + qrowB + lr) * NHEAD + h] = (float2){mB, lB};
    }
}

// ---------------------------------------------------------------- merge (4 parts)
__launch_bounds__(256)
__global__ void attn_merge4(const u16* __restrict__ P, const float2* __restrict__ ml,
                            u16* __restrict__ out) {
    const int i4 = blockIdx.x * 256 + threadIdx.x;   // 4-elem chunk index
    const size_t base = (size_t)i4 * 4;
    const int row = (int)(base / CDIM);
    const int head = (int)(base - (size_t)row * CDIM) >> 6;
    float2 a[KVSPLIT];
    float M = -3e38f;
#pragma unroll
    for (int z = 0; z < KVSPLIT; ++z) {
        a[z] = ml[((size_t)z * NROWS + row) * NHEAD + head];
        M = fmaxf(M, a[z].x);
    }
    float den = 0.f, e[KVSPLIT];
#pragma unroll
    for (int z = 0; z < KVSPLIT; ++z) {
        e[z] = exp2f(a[z].x - M);
        den += a[z].y * e[z];
    }
    const float rden = 1.f / den;
    float o0 = 0.f, o1 = 0.f, o2 = 0.f, o3 = 0.f;
#pragma unroll
    for (int z = 0; z < KVSPLIT; ++z) {
        ushort4 p = *(const ushort4*)(P + (size_t)z * NROWS * CDIM + base);
        o0 += bf2f(p.x) * e[z];
        o1 += bf2f(p.y) * e[z];
        o2 += bf2f(p.z) * e[z];
        o3 += bf2f(p.w) * e[z];
    }
    ushort4 o;
    o.x = f2bf(o0 * rden); o.y = f2bf(o1 * rden);
    o.z = f2bf(o2 * rden); o.w = f2bf(o3 * rden);
    *(ushort4*)(out + base) = o;
}

// ---------------------------------------------------------------- launch
extern "C" void kernel_launch(void* const* d_in, const int* in_sizes, int n_in,
                              void* d_out, int out_size, void* d_ws, size_t ws_size,
                              hipStream_t stream) {
    const float* x     = (const float*)d_in[0];
    const float* ctx   = (const float*)d_in[1];
    const float* ln1g  = (const float*)d_in[2];
    const float* ln1b  = (const float*)d_in[3];
    const float* ln2g  = (const float*)d_in[4];
    const float* ln2b  = (const float*)d_in[5];
    const float* ln3g  = (const float*)d_in[6];
    const float* ln3b  = (const float*)d_in[7];
    const float* sa_wq = (const float*)d_in[8];
    const float* sa_bq = (const float*)d_in[9];
    const float* sa_wk = (const float*)d_in[10];
    const float* sa_bk = (const float*)d_in[11];
    const float* sa_wv = (const float*)d_in[12];
    const float* sa_bv = (const float*)d_in[13];
    const float* sa_wo = (const float*)d_in[14];
    const float* sa_bo = (const float*)d_in[15];
    const float* xa_wq = (const float*)d_in[16];
    const float* xa_bq = (const float*)d_in[17];
    const float* xa_wk = (const float*)d_in[18];
    const float* xa_bk = (const float*)d_in[19];
    const float* xa_wv = (const float*)d_in[20];
    const float* xa_bv = (const float*)d_in[21];
    const float* xa_wo = (const float*)d_in[22];
    const float* xa_bo = (const float*)d_in[23];
    const float* m_w1  = (const float*)d_in[24];
    const float* m_b1  = (const float*)d_in[25];
    const float* m_w2  = (const float*)d_in[26];
    const float* m_b2  = (const float*)d_in[27];

    float* out_x   = (float*)d_out;
    float* out_ctx = out_x + (size_t)NROWS * CDIM;
    // d_out doubles as bf16 split-KV partial scratch (4 x NROWS*CDIM u16 =
    // exactly out_size bytes) until the final out_ctx memcpy / out_x GEMM.
    u16* Opart = (u16*)d_out;

    const size_t SZ_ACT  = (size_t)NROWS * CDIM * 2;
    const size_t SZ_WBIG = (size_t)HDIM * CDIM * 2;
    const size_t SZ_R    = (size_t)NROWS * CDIM * 4;
    const size_t NEEDED  = 5 * SZ_ACT + SZ_R + SZ_WBIG;
    if (ws_size < NEEDED) return;

    char* ws = (char*)d_ws;
    u16* qb    = (u16*)(ws);
    u16* kb    = (u16*)(ws + 1 * SZ_ACT);
    u16* vb    = (u16*)(ws + 2 * SZ_ACT);
    u16* ctxb  = (u16*)(ws + 3 * SZ_ACT);
    u16* hb    = qb;
    u16* lnbuf = (u16*)(ws + 4 * SZ_ACT);
    u16* attB  = lnbuf;
    float* R   = (float*)(ws + 5 * SZ_ACT);
    u16* Wq    = (u16*)(ws + 5 * SZ_ACT + SZ_R);   // pool: [Wq][Wk][Wv][Wo]
    u16* Wk    = Wq + (size_t)CDIM * CDIM;
    u16* Wv    = Wk + (size_t)CDIM * CDIM;
    u16* Wo    = Wv + (size_t)CDIM * CDIM;
    // ml (1.57MB) overlays Wq+Wk, which are DEAD once the QKV GEMM finished;
    // Wo stays intact for the o-projection after the merge.
    float2* ml = (float2*)Wq;

    const dim3 tb(256);
    GemmArgs ga;
    WT4 wg;

    cvt_copy<<<dim3(3072), tb, 0, stream>>>(ctx, ctxb, NROWS * CDIM / 4);

    // ---- self-attention
    ln_kernel<<<dim3(NROWS), tb, 0, stream>>>(x, ln1g, ln1b, lnbuf);
    wg.w[0] = sa_wq; wg.w[1] = sa_wk; wg.w[2] = sa_wv; wg.w[3] = sa_wo;
    wg.wt[0] = Wq;   wg.wt[1] = Wk;   wg.wt[2] = Wv;   wg.wt[3] = Wo;
    wtrans4<<<dim3(24, 24, 4), tb, 0, stream>>>(wg);
    ga = GemmArgs{};
    ga.A[0] = lnbuf; ga.BT[0] = Wq; ga.bias[0] = sa_bq; ga.out[0] = qb; ga.alpha[0] = QSCALE;
    ga.A[1] = lnbuf; ga.BT[1] = Wk; ga.bias[1] = sa_bk; ga.out[1] = kb; ga.alpha[1] = 1.f;
    ga.A[2] = lnbuf; ga.BT[2] = Wv; ga.bias[2] = sa_bv; ga.out[2] = vb; ga.alpha[2] = 1.f;
    ga.M = 4096; ga.N = 768; ga.K = 768;
    gemm_bt<0, 128><<<dim3(32, 6, 3), tb, 0, stream>>>(ga);
    attn_split<<<dim3(16, 24, KVSPLIT), tb, 0, stream>>>(qb, kb, vb, Opart, ml);
    attn_merge4<<<dim3(NROWS * CDIM / 1024), tb, 0, stream>>>(Opart, ml, attB);
    ga = GemmArgs{};
    ga.A[0] = attB; ga.BT[0] = Wo; ga.bias[0] = sa_bo; ga.res[0] = x; ga.out[0] = R; ga.alpha[0] = 1.f;
    ga.M = 4096; ga.N = 768; ga.K = 768;
    gemm_bt<1, 64, 64><<<dim3(64, 12, 1), tb, 0, stream>>>(ga);

    // ---- cross-attention
    ln_kernel<<<dim3(NROWS), tb, 0, stream>>>(R, ln2g, ln2b, lnbuf);
    wg.w[0] = xa_wq; wg.w[1] = xa_wk; wg.w[2] = xa_wv; wg.w[3] = xa_wo;
    wg.wt[0] = Wq;   wg.wt[1] = Wk;   wg.wt[2] = Wv;   wg.wt[3] = Wo;
    wtrans4<<<dim3(24, 24, 4), tb, 0, stream>>>(wg);
    ga = GemmArgs{};
    ga.A[0] = lnbuf; ga.BT[0] = Wq; ga.bias[0] = xa_bq; ga.out[0] = qb; ga.alpha[0] = QSCALE;
    ga.A[1] = ctxb;  ga.BT[1] = Wk; ga.bias[1] = xa_bk; ga.out[1] = kb; ga.alpha[1] = 1.f;
    ga.A[2] = ctxb;  ga.BT[2] = Wv; ga.bias[2] = xa_bv; ga.out[2] = vb; ga.alpha[2] = 1.f;
    ga.M = 4096; ga.N = 768; ga.K = 768;
    gemm_bt<0, 128><<<dim3(32, 6, 3), tb, 0, stream>>>(ga);
    attn_split<<<dim3(16, 24, KVSPLIT), tb, 0, stream>>>(qb, kb, vb, Opart, ml);
    attn_merge4<<<dim3(NROWS * CDIM / 1024), tb, 0, stream>>>(Opart, ml, attB);
    // context passthrough now that d_out's scratch role is over
    hipMemcpyAsync(out_ctx, ctx, (size_t)NROWS * CDIM * 4,
                   hipMemcpyDeviceToDevice, stream);
    ga = GemmArgs{};
    ga.A[0] = attB; ga.BT[0] = Wo; ga.bias[0] = xa_bo; ga.res[0] = R; ga.out[0] = R; ga.alpha[0] = 1.f;
    ga.M = 4096; ga.N = 768; ga.K = 768;
    gemm_bt<1, 64, 64><<<dim3(64, 12, 1), tb, 0, stream>>>(ga);

    // ---- MLP
    ln_kernel<<<dim3(NROWS), tb, 0, stream>>>(R, ln3g, ln3b, lnbuf);
    wtrans<<<dim3(96, 24), tb, 0, stream>>>(m_w1, Wq, 768, 3072);
    ga = GemmArgs{};
    ga.A[0] = lnbuf; ga.BT[0] = Wq; ga.bias[0] = m_b1; ga.out[0] = hb; ga.alpha[0] = 1.f;
    ga.M = 4096; ga.N = 3072; ga.K = 768;
    gemm_bt<2, 128><<<dim3(32, 24, 1), tb, 0, stream>>>(ga);
    wtrans<<<dim3(24, 96), tb, 0, stream>>>(m_w2, Wq, 3072, 768);
    ga = GemmArgs{};
    ga.A[0] = hb; ga.BT[0] = Wq; ga.bias[0] = m_b2; ga.res[0] = R; ga.out[0] = out_x; ga.alpha[0] = 1.f;
    ga.M = 4096; ga.N = 768; ga.K = 3072;
    gemm_bt<1, 64, 64><<<dim3(64, 12, 1), tb, 0, stream>>>(ga);

    (void)in_sizes; (void)n_in; (void)out_size;
}

// Round 15
// 337.853 us; speedup vs baseline: 1.5578x; 1.0085x over previous
//
#include <hip/hip_runtime.h>
#include <hip/hip_bf16.h>
#include <math.h>

#define CDIM 768
#define HDIM 3072
#define NROWS 4096   // B*T
#define TSEQ 2048
#define NHEAD 12
#define KVSPLIT 4
#define KVLEN (TSEQ / KVSPLIT)   // 512 rows per part

typedef unsigned short u16;
typedef unsigned int   u32;
typedef __attribute__((ext_vector_type(8))) short short8;
typedef __attribute__((ext_vector_type(4))) float f32x4;

// 1/sqrt(64) * log2(e): folds the softmax ln->log2 conversion into Q
#define QSCALE 0.18033688011112042f

static __device__ __forceinline__ u16 f2bf(float f) {
    u32 x = __float_as_uint(f);
    x += 0x7fffu + ((x >> 16) & 1u);
    return (u16)(x >> 16);
}
static __device__ __forceinline__ float bf2f(u16 x) {
    return __uint_as_float((u32)x << 16);
}
static __device__ __forceinline__ u32 cvt_pk_bf16(float lo, float hi) {
    u32 r;
    asm("v_cvt_pk_bf16_f32 %0, %1, %2" : "=v"(r) : "v"(lo), "v"(hi));
    return r;
}

#define GLL16(g, l)                                                            \
    __builtin_amdgcn_global_load_lds(                                          \
        (const __attribute__((address_space(1))) void*)(g),                    \
        (__attribute__((address_space(3))) void*)(l), 16, 0, 0)

// ---------------------------------------------------------------- packed pre-work helpers
// smem: at least 32*33 floats (4224 B), reused by all branches.
static __device__ void do_cvt(int blk, const float* __restrict__ in,
                              u16* __restrict__ out) {
    const int i = blk * 256 + threadIdx.x;   // float4 index, exact multiple
    float4 v = ((const float4*)in)[i];
    ushort4 o;
    o.x = f2bf(v.x); o.y = f2bf(v.y); o.z = f2bf(v.z); o.w = f2bf(v.w);
    ((ushort4*)out)[i] = o;
}

static __device__ void do_ln(int row, const float* __restrict__ x,
                             const float* __restrict__ g,
                             const float* __restrict__ bta,
                             u16* __restrict__ out, float* red) {
    const int tid = threadIdx.x;
    const float* xr = x + (size_t)row * CDIM;
    float v0 = xr[tid], v1 = xr[tid + 256], v2 = xr[tid + 512];
    float s = v0 + v1 + v2;
#pragma unroll
    for (int m = 1; m < 64; m <<= 1) s += __shfl_xor(s, m);
    if ((tid & 63) == 0) red[tid >> 6] = s;
    __syncthreads();
    const float mu = (red[0] + red[1] + red[2] + red[3]) * (1.f / CDIM);
    const float d0 = v0 - mu, d1 = v1 - mu, d2 = v2 - mu;
    float q = d0 * d0 + d1 * d1 + d2 * d2;
#pragma unroll
    for (int m = 1; m < 64; m <<= 1) q += __shfl_xor(q, m);
    if ((tid & 63) == 0) red[4 + (tid >> 6)] = q;
    __syncthreads();
    const float var = (red[4] + red[5] + red[6] + red[7]) * (1.f / CDIM);
    const float rstd = rsqrtf(var + 1e-5f);
    u16* orow = out + (size_t)row * CDIM;
    orow[tid]       = f2bf(d0 * rstd * g[tid]       + bta[tid]);
    orow[tid + 256] = f2bf(d1 * rstd * g[tid + 256] + bta[tid + 256]);
    orow[tid + 512] = f2bf(d2 * rstd * g[tid + 512] + bta[tid + 512]);
}

static __device__ void do_wt(int bx, int by, const float* __restrict__ w,
                             u16* __restrict__ wt, int K, int N, float* t /*32x33*/) {
    const int n0 = bx * 32, k0 = by * 32;
    const int tx = threadIdx.x & 31, ty = threadIdx.x >> 5;
#pragma unroll
    for (int i = ty; i < 32; i += 8)
        t[i * 33 + tx] = w[(size_t)(k0 + i) * N + n0 + tx];
    __syncthreads();
#pragma unroll
    for (int i = ty; i < 32; i += 8)
        wt[(size_t)(n0 + i) * K + k0 + tx] = f2bf(t[tx * 33 + i]);
}

// pre1: cvt_copy (3072) | LN1 (4096) | SA wtrans x4 (2304)
struct Pre1 {
    const float* ctx; u16* ctxb;
    const float* x; const float* g; const float* bta; u16* lnout;
    const float* w[4]; u16* wt[4];
};
__launch_bounds__(256)
__global__ void pre1_kernel(Pre1 p) {
    __shared__ float smem[32 * 33];
    int bid = blockIdx.x;
    if (bid < 3072) { do_cvt(bid, p.ctx, p.ctxb); return; }
    bid -= 3072;
    if (bid < 4096) { do_ln(bid, p.x, p.g, p.bta, p.lnout, smem); return; }
    bid -= 4096;
    const int z = bid / 576, rem = bid % 576;
    do_wt(rem % 24, rem / 24, p.w[z], p.wt[z], CDIM, CDIM, smem);
}

// pre2: LN (4096) | wtrans x4 (2304)
struct Pre2 {
    const float* x; const float* g; const float* bta; u16* lnout;
    const float* w[4]; u16* wt[4];
};
__launch_bounds__(256)
__global__ void pre2_kernel(Pre2 p) {
    __shared__ float smem[32 * 33];
    int bid = blockIdx.x;
    if (bid < 4096) { do_ln(bid, p.x, p.g, p.bta, p.lnout, smem); return; }
    bid -= 4096;
    const int z = bid / 576, rem = bid % 576;
    do_wt(rem % 24, rem / 24, p.w[z], p.wt[z], CDIM, CDIM, smem);
}

// pre3: LN3 (4096) | m_w1^T (2304: 96x24) | m_w2^T (2304: 24x96)
struct Pre3 {
    const float* x; const float* g; const float* bta; u16* lnout;
    const float* w1; u16* wt1;
    const float* w2; u16* wt2;
};
__launch_bounds__(256)
__global__ void pre3_kernel(Pre3 p) {
    __shared__ float smem[32 * 33];
    int bid = blockIdx.x;
    if (bid < 4096) { do_ln(bid, p.x, p.g, p.bta, p.lnout, smem); return; }
    bid -= 4096;
    if (bid < 2304) { do_wt(bid % 96, bid / 96, p.w1, p.wt1, CDIM, HDIM, smem); return; }
    bid -= 2304;
    do_wt(bid % 24, bid / 24, p.w2, p.wt2, HDIM, CDIM, smem);
}

// ---------------------------------------------------------------- GEMM (R12-verified)
struct GemmArgs {
    const u16* A[3];
    const u16* BT[3];
    const float* bias[3];
    const float* res[3];
    void* out[3];
    float alpha[3];
    int M, N, K;
};

// EPI: 0 = (s+bias)*alpha -> bf16 ; 1 = res + s + bias -> f32 ; 2 = gelu -> bf16
template <int EPI, int BM, int BN = 128>
__launch_bounds__(256)
__global__ void gemm_bt(GemmArgs ga) {
    constexpr int MF = BM / 32, NF = BN / 32;
    __shared__ u16 Abuf[BM * 32];
    __shared__ u16 Bbuf[BN * 32];
    const int z = blockIdx.z;
    const u16* __restrict__ A  = ga.A[z];
    const u16* __restrict__ BT = ga.BT[z];
    const float* __restrict__ bias = ga.bias[z];
    const float* __restrict__ res  = ga.res[z];
    void* outv = ga.out[z];
    const float alpha = ga.alpha[z];
    const int N = ga.N, K = ga.K;

    const int tid = threadIdx.x;
    const int lane = tid & 63, w = tid >> 6;
    const int m0 = blockIdx.x * BM, n0 = blockIdx.y * BN;
    const int wr = (w >> 1) * (BM / 2), wc = (w & 1) * (BN / 2);
    const int lr = lane & 15, lc = lane >> 4;

    const int srowA = (BM == 128) ? (w * 32 + (lane >> 2)) : (tid >> 2);
    const int srowB = (BN == 128) ? (w * 32 + (lane >> 2)) : (tid >> 2);
    const int scol = (lane & 3) * 8;
    const u16* Ag = A + (size_t)(m0 + srowA) * K + scol;
    const u16* Bg = BT + (size_t)(n0 + srowB) * K + scol;
    char* Ab = (char*)Abuf + w * (BM == 128 ? 2048 : 1024);
    char* Bb = (char*)Bbuf + w * (BN == 128 ? 2048 : 1024);

    f32x4 acc[MF][NF];
#pragma unroll
    for (int m = 0; m < MF; ++m)
#pragma unroll
        for (int n = 0; n < NF; ++n) acc[m][n] = (f32x4){0.f, 0.f, 0.f, 0.f};

    const int nk = K >> 5;
    for (int kt = 0; kt < nk; ++kt) {
        const int ko = kt * 32;
        GLL16(Ag + ko, Ab);
        if constexpr (BM == 128) GLL16(Ag + 16 * K + ko, Ab + 1024);
        GLL16(Bg + ko, Bb);
        if constexpr (BN == 128) GLL16(Bg + 16 * K + ko, Bb + 1024);
        __syncthreads();
        short8 af[MF], bfv[NF];
#pragma unroll
        for (int m = 0; m < MF; ++m)
            af[m] = *(const short8*)((const char*)Abuf +
                                     (size_t)(wr + m * 16 + lr) * 64 + lc * 16);
#pragma unroll
        for (int n = 0; n < NF; ++n)
            bfv[n] = *(const short8*)((const char*)Bbuf +
                                      (size_t)(wc + n * 16 + lr) * 64 + lc * 16);
#pragma unroll
        for (int m = 0; m < MF; ++m)
#pragma unroll
            for (int n = 0; n < NF; ++n)
                acc[m][n] = __builtin_amdgcn_mfma_f32_16x16x32_bf16(
                    af[m], bfv[n], acc[m][n], 0, 0, 0);
        __syncthreads();
    }

#pragma unroll
    for (int n = 0; n < NF; ++n) {
        const int gc = n0 + wc + n * 16 + lr;
        const float bs = bias[gc];
#pragma unroll
        for (int m = 0; m < MF; ++m) {
            const int gr = m0 + wr + m * 16 + lc * 4;
#pragma unroll
            for (int r = 0; r < 4; ++r) {
                float v = (acc[m][n][r] + bs) * alpha;
                const size_t idx = (size_t)(gr + r) * N + gc;
                if constexpr (EPI == 0) {
                    ((u16*)outv)[idx] = f2bf(v);
                } else if constexpr (EPI == 1) {
                    ((float*)outv)[idx] = res[idx] + v;
                } else {
                    float gel = 0.5f * v * (1.0f + erff(v * 0.70710678118654752f));
                    ((u16*)outv)[idx] = f2bf(gel);
                }
            }
        }
    }
}

// ---------------------------------------------------------------- attention helpers
static __device__ __forceinline__ void softmax_pack(f32x4 sf[4], float& mrow,
                                                    float& lrow, f32x4 oacc[4],
                                                    short8& p0, short8& p1) {
    float pm;
    {
        float a0 = fmaxf(fmaxf(sf[0][0], sf[0][1]), fmaxf(sf[0][2], sf[0][3]));
        float a1 = fmaxf(fmaxf(sf[1][0], sf[1][1]), fmaxf(sf[1][2], sf[1][3]));
        float a2 = fmaxf(fmaxf(sf[2][0], sf[2][1]), fmaxf(sf[2][2], sf[2][3]));
        float a3 = fmaxf(fmaxf(sf[3][0], sf[3][1]), fmaxf(sf[3][2], sf[3][3]));
        pm = fmaxf(fmaxf(a0, a1), fmaxf(a2, a3));
        pm = fmaxf(pm, __shfl_xor(pm, 16));
        pm = fmaxf(pm, __shfl_xor(pm, 32));
    }
    // defer-max: only rescale when some q-row's max grew (wave-uniform)
    if (!__all(pm <= mrow)) {
        const float mn = fmaxf(mrow, pm);
        const float corr = exp2f(mrow - mn);
        mrow = mn;
        lrow *= corr;
#pragma unroll
        for (int fd = 0; fd < 4; ++fd)
#pragma unroll
            for (int r = 0; r < 4; ++r) oacc[fd][r] *= corr;
    }
#pragma unroll
    for (int fn = 0; fn < 4; ++fn)
#pragma unroll
        for (int r = 0; r < 4; ++r) sf[fn][r] = exp2f(sf[fn][r] - mrow);
    float rs;
    {
        float s0 = (sf[0][0] + sf[0][1]) + (sf[0][2] + sf[0][3]);
        float s1 = (sf[1][0] + sf[1][1]) + (sf[1][2] + sf[1][3]);
        float s2 = (sf[2][0] + sf[2][1]) + (sf[2][2] + sf[2][3]);
        float s3 = (sf[3][0] + sf[3][1]) + (sf[3][2] + sf[3][3]);
        rs = (s0 + s1) + (s2 + s3);
        rs += __shfl_xor(rs, 16);
        rs += __shfl_xor(rs, 32);
    }
    lrow += rs;
    int4 pw0, pw1;
    pw0.x = cvt_pk_bf16(sf[0][0], sf[0][1]);
    pw0.y = cvt_pk_bf16(sf[0][2], sf[0][3]);
    pw0.z = cvt_pk_bf16(sf[1][0], sf[1][1]);
    pw0.w = cvt_pk_bf16(sf[1][2], sf[1][3]);
    pw1.x = cvt_pk_bf16(sf[2][0], sf[2][1]);
    pw1.y = cvt_pk_bf16(sf[2][2], sf[2][3]);
    pw1.z = cvt_pk_bf16(sf[3][0], sf[3][1]);
    pw1.w = cvt_pk_bf16(sf[3][2], sf[3][3]);
    p0 = *(short8*)&pw0;
    p1 = *(short8*)&pw1;
}

// ---------------------------------------------------------------- attention (split-KV, 128q/block)
__launch_bounds__(256, 4)
__global__ void attn_split(const u16* __restrict__ Qb, const u16* __restrict__ Kb,
                           const u16* __restrict__ Vb, u16* __restrict__ Opart,
                           float2* __restrict__ ml) {
    __shared__ u16 Klds[64 * 72];
    __shared__ u16 Vt[64 * 72];
    const int tid = threadIdx.x;
    const int lane = tid & 63, w = tid >> 6;
    const int lr = lane & 15, lc = lane >> 4;
    const int b = blockIdx.y / NHEAD, h = blockIdx.y % NHEAD;
    const int z = blockIdx.z;
    const size_t qrowA = (size_t)b * TSEQ + blockIdx.x * 128 + w * 16;
    const size_t qrowB = qrowA + 64;
    const size_t krow0 = (size_t)b * TSEQ + (size_t)z * KVLEN;
    const int hc = h * 64;

    short8 qa0, qa1, qb0, qb1;
    {
        const u16* qp = Qb + (qrowA + lr) * CDIM + hc + lc * 8;
        qa0 = *(const short8*)qp;
        qa1 = *(const short8*)(qp + 32);
        const u16* qp2 = Qb + (qrowB + lr) * CDIM + hc + lc * 8;
        qb0 = *(const short8*)qp2;
        qb1 = *(const short8*)(qp2 + 32);
    }
    f32x4 oaccA[4], oaccB[4];
#pragma unroll
    for (int r = 0; r < 4; ++r) {
        oaccA[r] = (f32x4){0.f, 0.f, 0.f, 0.f};
        oaccB[r] = (f32x4){0.f, 0.f, 0.f, 0.f};
    }
    float mA = -3e38f, lA = 0.f, mB = -3e38f, lB = 0.f;

    const int stg_r = tid >> 2, stg_s = tid & 3;
    const u16* kg = Kb + (krow0 + stg_r) * CDIM + hc + stg_s * 16;
    const u16* vg = Vb + (krow0 + stg_r) * CDIM + hc + stg_s * 16;
    uint4 ka0 = *(const uint4*)kg, ka1 = *(const uint4*)(kg + 8);
    uint4 va0 = *(const uint4*)vg, va1 = *(const uint4*)(vg + 8);
    const int sig = ((stg_r >> 5) << 5) + (((stg_r >> 2) & 3) << 3) +
                    (((stg_r >> 4) & 1) << 2) + (stg_r & 3);
    char* vdst = (char*)Vt + ((2 * sig) ^ (stg_s << 5)) +
                 (size_t)(stg_s * 16) * 144;

    for (int kt = 0; kt < KVLEN / 64; ++kt) {
        __syncthreads();
        {
            *(uint4*)&Klds[stg_r * 72 + stg_s * 16]     = ka0;
            *(uint4*)&Klds[stg_r * 72 + stg_s * 16 + 8] = ka1;
            u16 tmp[16];
            *(uint4*)(tmp)     = va0;
            *(uint4*)(tmp + 8) = va1;
#pragma unroll
            for (int j = 0; j < 16; ++j)
                *(u16*)(vdst + (size_t)j * 144) = tmp[j];
        }
        if (kt < KVLEN / 64 - 1) {
            kg += 64 * CDIM; vg += 64 * CDIM;
            ka0 = *(const uint4*)kg; ka1 = *(const uint4*)(kg + 8);
            va0 = *(const uint4*)vg; va1 = *(const uint4*)(vg + 8);
        }
        __syncthreads();

        // S^T = K * Q^T for both q-groups; each K fragment read used twice
        f32x4 sfA[4], sfB[4];
#pragma unroll
        for (int fn = 0; fn < 4; ++fn) {
            const u16* kr = &Klds[(lr + fn * 16) * 72 + lc * 8];
            short8 kb0 = *(const short8*)kr;
            short8 kb1 = *(const short8*)(kr + 32);
            f32x4 t = (f32x4){0.f, 0.f, 0.f, 0.f};
            t = __builtin_amdgcn_mfma_f32_16x16x32_bf16(kb0, qa0, t, 0, 0, 0);
            t = __builtin_amdgcn_mfma_f32_16x16x32_bf16(kb1, qa1, t, 0, 0, 0);
            sfA[fn] = t;
            f32x4 u = (f32x4){0.f, 0.f, 0.f, 0.f};
            u = __builtin_amdgcn_mfma_f32_16x16x32_bf16(kb0, qb0, u, 0, 0, 0);
            u = __builtin_amdgcn_mfma_f32_16x16x32_bf16(kb1, qb1, u, 0, 0, 0);
            sfB[fn] = u;
        }

        short8 pA0, pA1, pB0, pB1;
        softmax_pack(sfA, mA, lA, oaccA, pA0, pA1);
        softmax_pack(sfB, mB, lB, oaccB, pB0, pB1);

        // O^T += V^T * P^T ; each V fragment read used twice
#pragma unroll
        for (int fd = 0; fd < 4; ++fd) {
            const char* vtb = (const char*)Vt + (size_t)(lr + fd * 16) * 144;
            short8 vb0 = *(const short8*)(vtb + ((lc * 16) ^ (fd * 32)));
            short8 vb1 = *(const short8*)(vtb + ((lc * 16 + 64) ^ (fd * 32)));
            oaccA[fd] = __builtin_amdgcn_mfma_f32_16x16x32_bf16(vb0, pA0, oaccA[fd], 0, 0, 0);
            oaccA[fd] = __builtin_amdgcn_mfma_f32_16x16x32_bf16(vb1, pA1, oaccA[fd], 0, 0, 0);
            oaccB[fd] = __builtin_amdgcn_mfma_f32_16x16x32_bf16(vb0, pB0, oaccB[fd], 0, 0, 0);
            oaccB[fd] = __builtin_amdgcn_mfma_f32_16x16x32_bf16(vb1, pB1, oaccB[fd], 0, 0, 0);
        }
    }

    // epilogue: UNNORMALIZED bf16 partials + (m,l) for both groups
    u16* oA = Opart + (size_t)z * NROWS * CDIM + (qrowA + lr) * CDIM + hc + lc * 4;
    u16* oB = Opart + (size_t)z * NROWS * CDIM + (qrowB + lr) * CDIM + hc + lc * 4;
#pragma unroll
    for (int fd = 0; fd < 4; ++fd) {
        ushort4 o;
        o.x = f2bf(oaccA[fd][0]); o.y = f2bf(oaccA[fd][1]);
        o.z = f2bf(oaccA[fd][2]); o.w = f2bf(oaccA[fd][3]);
        *(ushort4*)(oA + fd * 16) = o;
        o.x = f2bf(oaccB[fd][0]); o.y = f2bf(oaccB[fd][1]);
        o.z = f2bf(oaccB[fd][2]); o.w = f2bf(oaccB[fd][3]);
        *(ushort4*)(oB + fd * 16) = o;
    }
    if (lc == 0) {
        ml[((size_t)z * NROWS + qrowA + lr) * NHEAD + h] = (float2){mA, lA};
        ml[((size_t)z * NROWS + qrowB + lr) * NHEAD + h] = (float2){mB, lB};
    }
}

// ---------------------------------------------------------------- merge (4 parts)
__launch_bounds__(256)
__global__ void attn_merge4(const u16* __restrict__ P, const float2* __restrict__ ml,
                            u16* __restrict__ out) {
    const int i4 = blockIdx.x * 256 + threadIdx.x;   // 4-elem chunk index
    const size_t base = (size_t)i4 * 4;
    const int row = (int)(base / CDIM);
    const int head = (int)(base - (size_t)row * CDIM) >> 6;
    float2 a[KVSPLIT];
    float M = -3e38f;
#pragma unroll
    for (int z = 0; z < KVSPLIT; ++z) {
        a[z] = ml[((size_t)z * NROWS + row) * NHEAD + head];
        M = fmaxf(M, a[z].x);
    }
    float den = 0.f, e[KVSPLIT];
#pragma unroll
    for (int z = 0; z < KVSPLIT; ++z) {
        e[z] = exp2f(a[z].x - M);
        den += a[z].y * e[z];
    }
    const float rden = 1.f / den;
    float o0 = 0.f, o1 = 0.f, o2 = 0.f, o3 = 0.f;
#pragma unroll
    for (int z = 0; z < KVSPLIT; ++z) {
        ushort4 p = *(const ushort4*)(P + (size_t)z * NROWS * CDIM + base);
        o0 += bf2f(p.x) * e[z];
        o1 += bf2f(p.y) * e[z];
        o2 += bf2f(p.z) * e[z];
        o3 += bf2f(p.w) * e[z];
    }
    ushort4 o;
    o.x = f2bf(o0 * rden); o.y = f2bf(o1 * rden);
    o.z = f2bf(o2 * rden); o.w = f2bf(o3 * rden);
    *(ushort4*)(out + base) = o;
}

// ---------------------------------------------------------------- launch
extern "C" void kernel_launch(void* const* d_in, const int* in_sizes, int n_in,
                              void* d_out, int out_size, void* d_ws, size_t ws_size,
                              hipStream_t stream) {
    const float* x     = (const float*)d_in[0];
    const float* ctx   = (const float*)d_in[1];
    const float* ln1g  = (const float*)d_in[2];
    const float* ln1b  = (const float*)d_in[3];
    const float* ln2g  = (const float*)d_in[4];
    const float* ln2b  = (const float*)d_in[5];
    const float* ln3g  = (const float*)d_in[6];
    const float* ln3b  = (const float*)d_in[7];
    const float* sa_wq = (const float*)d_in[8];
    const float* sa_bq = (const float*)d_in[9];
    const float* sa_wk = (const float*)d_in[10];
    const float* sa_bk = (const float*)d_in[11];
    const float* sa_wv = (const float*)d_in[12];
    const float* sa_bv = (const float*)d_in[13];
    const float* sa_wo = (const float*)d_in[14];
    const float* sa_bo = (const float*)d_in[15];
    const float* xa_wq = (const float*)d_in[16];
    const float* xa_bq = (const float*)d_in[17];
    const float* xa_wk = (const float*)d_in[18];
    const float* xa_bk = (const float*)d_in[19];
    const float* xa_wv = (const float*)d_in[20];
    const float* xa_bv = (const float*)d_in[21];
    const float* xa_wo = (const float*)d_in[22];
    const float* xa_bo = (const float*)d_in[23];
    const float* m_w1  = (const float*)d_in[24];
    const float* m_b1  = (const float*)d_in[25];
    const float* m_w2  = (const float*)d_in[26];
    const float* m_b2  = (const float*)d_in[27];

    float* out_x   = (float*)d_out;
    float* out_ctx = out_x + (size_t)NROWS * CDIM;
    // d_out doubles as scratch: bf16 split-KV partials during attention,
    // then m_w2^T (4.7MB, in the out_ctx half) during the MLP. The ctx
    // passthrough memcpy is the LAST op.
    u16* Opart = (u16*)d_out;
    u16* W2s   = (u16*)out_ctx;

    const size_t SZ_ACT  = (size_t)NROWS * CDIM * 2;
    const size_t SZ_WBIG = (size_t)HDIM * CDIM * 2;
    const size_t SZ_R    = (size_t)NROWS * CDIM * 4;
    const size_t NEEDED  = 5 * SZ_ACT + SZ_R + SZ_WBIG;
    if (ws_size < NEEDED) return;

    char* ws = (char*)d_ws;
    u16* qb    = (u16*)(ws);
    u16* kb    = (u16*)(ws + 1 * SZ_ACT);
    u16* vb    = (u16*)(ws + 2 * SZ_ACT);
    u16* ctxb  = (u16*)(ws + 3 * SZ_ACT);
    u16* hb    = qb;
    u16* lnbuf = (u16*)(ws + 4 * SZ_ACT);
    u16* attB  = lnbuf;
    float* R   = (float*)(ws + 5 * SZ_ACT);
    u16* Wq    = (u16*)(ws + 5 * SZ_ACT + SZ_R);   // pool: [Wq][Wk][Wv][Wo]
    u16* Wk    = Wq + (size_t)CDIM * CDIM;
    u16* Wv    = Wk + (size_t)CDIM * CDIM;
    u16* Wo    = Wv + (size_t)CDIM * CDIM;
    // ml (1.57MB) overlays Wq+Wk (dead after the QKV GEMM); Wo survives.
    float2* ml = (float2*)Wq;

    const dim3 tb(256);
    GemmArgs ga;

    // ---- self-attention
    Pre1 p1;
    p1.ctx = ctx; p1.ctxb = ctxb;
    p1.x = x; p1.g = ln1g; p1.bta = ln1b; p1.lnout = lnbuf;
    p1.w[0] = sa_wq; p1.w[1] = sa_wk; p1.w[2] = sa_wv; p1.w[3] = sa_wo;
    p1.wt[0] = Wq;   p1.wt[1] = Wk;   p1.wt[2] = Wv;   p1.wt[3] = Wo;
    pre1_kernel<<<dim3(3072 + 4096 + 2304), tb, 0, stream>>>(p1);
    ga = GemmArgs{};
    ga.A[0] = lnbuf; ga.BT[0] = Wq; ga.bias[0] = sa_bq; ga.out[0] = qb; ga.alpha[0] = QSCALE;
    ga.A[1] = lnbuf; ga.BT[1] = Wk; ga.bias[1] = sa_bk; ga.out[1] = kb; ga.alpha[1] = 1.f;
    ga.A[2] = lnbuf; ga.BT[2] = Wv; ga.bias[2] = sa_bv; ga.out[2] = vb; ga.alpha[2] = 1.f;
    ga.M = 4096; ga.N = 768; ga.K = 768;
    gemm_bt<0, 128, 64><<<dim3(32, 12, 3), tb, 0, stream>>>(ga);
    attn_split<<<dim3(16, 24, KVSPLIT), tb, 0, stream>>>(qb, kb, vb, Opart, ml);
    attn_merge4<<<dim3(NROWS * CDIM / 1024), tb, 0, stream>>>(Opart, ml, attB);
    ga = GemmArgs{};
    ga.A[0] = attB; ga.BT[0] = Wo; ga.bias[0] = sa_bo; ga.res[0] = x; ga.out[0] = R; ga.alpha[0] = 1.f;
    ga.M = 4096; ga.N = 768; ga.K = 768;
    gemm_bt<1, 64, 64><<<dim3(64, 12, 1), tb, 0, stream>>>(ga);

    // ---- cross-attention
    Pre2 p2;
    p2.x = R; p2.g = ln2g; p2.bta = ln2b; p2.lnout = lnbuf;
    p2.w[0] = xa_wq; p2.w[1] = xa_wk; p2.w[2] = xa_wv; p2.w[3] = xa_wo;
    p2.wt[0] = Wq;   p2.wt[1] = Wk;   p2.wt[2] = Wv;   p2.wt[3] = Wo;
    pre2_kernel<<<dim3(4096 + 2304), tb, 0, stream>>>(p2);
    ga = GemmArgs{};
    ga.A[0] = lnbuf; ga.BT[0] = Wq; ga.bias[0] = xa_bq; ga.out[0] = qb; ga.alpha[0] = QSCALE;
    ga.A[1] = ctxb;  ga.BT[1] = Wk; ga.bias[1] = xa_bk; ga.out[1] = kb; ga.alpha[1] = 1.f;
    ga.A[2] = ctxb;  ga.BT[2] = Wv; ga.bias[2] = xa_bv; ga.out[2] = vb; ga.alpha[2] = 1.f;
    ga.M = 4096; ga.N = 768; ga.K = 768;
    gemm_bt<0, 128, 64><<<dim3(32, 12, 3), tb, 0, stream>>>(ga);
    attn_split<<<dim3(16, 24, KVSPLIT), tb, 0, stream>>>(qb, kb, vb, Opart, ml);
    attn_merge4<<<dim3(NROWS * CDIM / 1024), tb, 0, stream>>>(Opart, ml, attB);
    ga = GemmArgs{};
    ga.A[0] = attB; ga.BT[0] = Wo; ga.bias[0] = xa_bo; ga.res[0] = R; ga.out[0] = R; ga.alpha[0] = 1.f;
    ga.M = 4096; ga.N = 768; ga.K = 768;
    gemm_bt<1, 64, 64><<<dim3(64, 12, 1), tb, 0, stream>>>(ga);

    // ---- MLP (m_w2^T staged in the dead out_ctx half of d_out)
    Pre3 p3;
    p3.x = R; p3.g = ln3g; p3.bta = ln3b; p3.lnout = lnbuf;
    p3.w1 = m_w1; p3.wt1 = Wq;
    p3.w2 = m_w2; p3.wt2 = W2s;
    pre3_kernel<<<dim3(4096 + 2304 + 2304), tb, 0, stream>>>(p3);
    ga = GemmArgs{};
    ga.A[0] = lnbuf; ga.BT[0] = Wq; ga.bias[0] = m_b1; ga.out[0] = hb; ga.alpha[0] = 1.f;
    ga.M = 4096; ga.N = 3072; ga.K = 768;
    gemm_bt<2, 128><<<dim3(32, 24, 1), tb, 0, stream>>>(ga);
    ga = GemmArgs{};
    ga.A[0] = hb; ga.BT[0] = W2s; ga.bias[0] = m_b2; ga.res[0] = R; ga.out[0] = out_x; ga.alpha[0] = 1.f;
    ga.M = 4096; ga.N = 768; ga.K = 3072;
    gemm_bt<1, 64, 64><<<dim3(64, 12, 1), tb, 0, stream>>>(ga);
    // context passthrough LAST (d_out scratch roles all expired)
    hipMemcpyAsync(out_ctx, ctx, (size_t)NROWS * CDIM * 4,
                   hipMemcpyDeviceToDevice, stream);

    (void)in_sizes; (void)n_in; (void)out_size;
}